// Round 1
// baseline (310.102 us; speedup 1.0000x reference)
//
#include <hip/hip_runtime.h>
#include <hip/hip_bf16.h>
#include <math.h>

// GAT block: N=50000 nodes, E=800000 edges, H_IN=64, HEADS=4, C=16 (F=64 out)
//
// out = ELU_0.1( segsum(exp(leaky(a_s[src]+a_d[dst]))*h[src])/segsum(exp(...))
//               + conv_bias + x@skip_W + skip_b )
// with implicit self-loops. Softmax max-subtraction dropped (e is O(1), exp safe;
// mathematically identical). Unnormalized aggregation; divide once in finalize.

#define BLK 256

// ---------------- K0: normalize edge_index to int32 --------------------------
// Detect int64 vs int32 on device: if the buffer is little-endian int64 with
// values < 2^31, every odd int32 word is 0. 64 samples => certainty.
__global__ void convert_edges(const int* __restrict__ ei_raw,
                              int* __restrict__ e32, int total) {
    __shared__ int s_is64;
    if (threadIdx.x == 0) {
        int all0 = 1;
        for (int i = 1; i < 128; i += 2) all0 &= (ei_raw[i] == 0);
        s_is64 = all0;
    }
    __syncthreads();
    const int is64 = s_is64;
    const long long* e64 = (const long long*)ei_raw;
    int gid = blockIdx.x * BLK + threadIdx.x;
    if (gid < total) e32[gid] = is64 ? (int)e64[gid] : ei_raw[gid];
}

// ---------------- K1: node transform + self-loop init ------------------------
// One wave (64 lanes) per row. lane j owns output feature j.
// h = x@W ; base = x@skip_W + skip_b + conv_bias
// a_src/a_dst via 16-lane butterfly reduce; denom/agg init with self-loop.
__global__ __launch_bounds__(BLK) void node_kernel(
    const float* __restrict__ x, const float* __restrict__ W,
    const float* __restrict__ att_src, const float* __restrict__ att_dst,
    const float* __restrict__ conv_bias, const float* __restrict__ skip_W,
    const float* __restrict__ skip_b,
    float* __restrict__ h, float* __restrict__ base,
    float* __restrict__ a_src, float* __restrict__ a_dst,
    float* __restrict__ denom, float* __restrict__ agg, int n_nodes) {
    __shared__ float sW[64][64];
    __shared__ float sSW[64][64];
    __shared__ float sAttS[64], sAttD[64], sBias[64];
    const int tid = threadIdx.x;
    for (int i = tid; i < 4096; i += BLK) {
        sW[i >> 6][i & 63] = W[i];
        sSW[i >> 6][i & 63] = skip_W[i];
    }
    if (tid < 64) {
        sAttS[tid] = att_src[tid];
        sAttD[tid] = att_dst[tid];
        sBias[tid] = conv_bias[tid] + skip_b[tid];
    }
    __syncthreads();

    const int wave = tid >> 6, lane = tid & 63;
    const int row = blockIdx.x * 4 + wave;
    if (row >= n_nodes) return;

    const float xv = x[row * 64 + lane];
    float accH = 0.f, accS = 0.f;
#pragma unroll
    for (int k = 0; k < 64; ++k) {
        const float xk = __shfl(xv, k);
        accH = fmaf(xk, sW[k][lane], accH);
        accS = fmaf(xk, sSW[k][lane], accS);
    }
    h[row * 64 + lane] = accH;
    base[row * 64 + lane] = accS + sBias[lane];

    // per-head (16-lane group) butterfly reduction -> every lane holds the sum
    float p = accH * sAttS[lane];
    float q = accH * sAttD[lane];
#pragma unroll
    for (int o = 1; o < 16; o <<= 1) {
        p += __shfl_xor(p, o);
        q += __shfl_xor(q, o);
    }
    float e = p + q;                       // self-loop score
    e = e > 0.f ? e : 0.2f * e;            // leaky_relu
    const float w = __expf(e);
    if ((lane & 15) == 0) {
        const int head = lane >> 4;
        a_src[row * 4 + head] = p;
        a_dst[row * 4 + head] = q;
        denom[row * 4 + head] = w;         // self-loop seeds the softmax denom
    }
    agg[row * 64 + lane] = w * accH;       // self-loop seeds the aggregation
}

// ---------------- K2: edge aggregation (atomics) -----------------------------
// One wave per edge; lane j handles feature j (head = j>>4).
__global__ __launch_bounds__(BLK) void edge_kernel(
    const int* __restrict__ esrc, const int* __restrict__ edst,
    const float* __restrict__ h, const float* __restrict__ a_src,
    const float* __restrict__ a_dst, float* __restrict__ agg,
    float* __restrict__ denom, int n_edges) {
    const long long gid = (long long)blockIdx.x * BLK + threadIdx.x;
    const long long eix = gid >> 6;
    if (eix >= n_edges) return;
    const int lane = (int)(gid & 63);
    const int head = lane >> 4;
    const int s = esrc[eix];
    const int d = edst[eix];
    float e = a_src[s * 4 + head] + a_dst[d * 4 + head];
    e = e > 0.f ? e : 0.2f * e;
    const float w = __expf(e);
    const float hv = h[s * 64 + lane];
    atomicAdd(&agg[d * 64 + lane], w * hv);
    if ((lane & 15) == 0) atomicAdd(&denom[d * 4 + head], w);
}

// ---------------- K3: normalize + residual + ELU -----------------------------
__global__ __launch_bounds__(BLK) void finalize_kernel(
    const float* __restrict__ agg, const float* __restrict__ denom,
    const float* __restrict__ base, float* __restrict__ out, int total) {
    const int gid = blockIdx.x * BLK + threadIdx.x;
    if (gid >= total) return;
    const int n = gid >> 6;
    const int head = (gid & 63) >> 4;
    const float v = agg[gid] / denom[n * 4 + head] + base[gid];
    out[gid] = v > 0.f ? v : 0.1f * expm1f(v);
}

extern "C" void kernel_launch(void* const* d_in, const int* in_sizes, int n_in,
                              void* d_out, int out_size, void* d_ws, size_t ws_size,
                              hipStream_t stream) {
    const float* x         = (const float*)d_in[0];
    const int*   ei_raw    = (const int*)d_in[1];
    const float* W         = (const float*)d_in[2];
    const float* att_src   = (const float*)d_in[3];
    const float* att_dst   = (const float*)d_in[4];
    const float* conv_bias = (const float*)d_in[5];
    const float* skip_W    = (const float*)d_in[6];
    const float* skip_b    = (const float*)d_in[7];

    const int n_nodes = in_sizes[0] / 64;   // 50000
    const int n_edges = in_sizes[1] / 2;    // 800000

    float* ws    = (float*)d_ws;
    float* h     = ws;                       // n_nodes*64
    float* base  = h + (size_t)n_nodes * 64; // n_nodes*64
    float* a_src = base + (size_t)n_nodes * 64;  // n_nodes*4
    float* a_dst = a_src + (size_t)n_nodes * 4;  // n_nodes*4
    float* denom = a_dst + (size_t)n_nodes * 4;  // n_nodes*4
    int*   e32   = (int*)(denom + (size_t)n_nodes * 4); // 2*n_edges ints
    float* agg   = (float*)d_out;            // accumulate unnormalized agg in-place

    const int totalE = 2 * n_edges;
    convert_edges<<<(totalE + BLK - 1) / BLK, BLK, 0, stream>>>(ei_raw, e32, totalE);

    node_kernel<<<(n_nodes + 3) / 4, BLK, 0, stream>>>(
        x, W, att_src, att_dst, conv_bias, skip_W, skip_b,
        h, base, a_src, a_dst, denom, agg, n_nodes);

    const long long edgeThreads = (long long)n_edges * 64;
    edge_kernel<<<(int)((edgeThreads + BLK - 1) / BLK), BLK, 0, stream>>>(
        e32, e32 + n_edges, h, a_src, a_dst, agg, denom, n_edges);

    const int total = n_nodes * 64;
    finalize_kernel<<<(total + BLK - 1) / BLK, BLK, 0, stream>>>(
        agg, denom, base, (float*)d_out, total);
}

// Round 2
// 237.346 us; speedup vs baseline: 1.3065x; 1.3065x over previous
//
#include <hip/hip_runtime.h>
#include <hip/hip_bf16.h>
#include <math.h>

// GAT block: N=50000, E=800000, H_IN=64, HEADS=4, C=16 (F=64 out)
// Round 2: replace 51M f32 atomicAdds (atomic-bound, 214us) with device
// counting-sort by dst (CSR) + register-accumulating gather aggregation.

#define BLK 256

// ---------------- K0: normalize edge_index to int32 --------------------------
__global__ void convert_edges(const int* __restrict__ ei_raw,
                              int* __restrict__ e32, int total) {
    __shared__ int s_is64;
    if (threadIdx.x == 0) {
        int all0 = 1;
        for (int i = 1; i < 128; i += 2) all0 &= (ei_raw[i] == 0);
        s_is64 = all0;
    }
    __syncthreads();
    const int is64 = s_is64;
    const long long* e64 = (const long long*)ei_raw;
    int gid = blockIdx.x * BLK + threadIdx.x;
    if (gid < total) e32[gid] = is64 ? (int)e64[gid] : ei_raw[gid];
}

// ---------------- K1: node transform -----------------------------------------
// One wave per row: h = x@W ; base(=d_out) = x@skip_W + skip_b + conv_bias
// a_src/a_dst via 16-lane butterfly reduce.
__global__ __launch_bounds__(BLK) void node_kernel(
    const float* __restrict__ x, const float* __restrict__ W,
    const float* __restrict__ att_src, const float* __restrict__ att_dst,
    const float* __restrict__ conv_bias, const float* __restrict__ skip_W,
    const float* __restrict__ skip_b,
    float* __restrict__ h, float* __restrict__ base,
    float* __restrict__ a_src, float* __restrict__ a_dst, int n_nodes) {
    __shared__ float sW[64][64];
    __shared__ float sSW[64][64];
    __shared__ float sAttS[64], sAttD[64], sBias[64];
    const int tid = threadIdx.x;
    for (int i = tid; i < 4096; i += BLK) {
        sW[i >> 6][i & 63] = W[i];
        sSW[i >> 6][i & 63] = skip_W[i];
    }
    if (tid < 64) {
        sAttS[tid] = att_src[tid];
        sAttD[tid] = att_dst[tid];
        sBias[tid] = conv_bias[tid] + skip_b[tid];
    }
    __syncthreads();

    const int wave = tid >> 6, lane = tid & 63;
    const int row = blockIdx.x * 4 + wave;
    if (row >= n_nodes) return;

    const float xv = x[row * 64 + lane];
    float accH = 0.f, accS = 0.f;
#pragma unroll
    for (int k = 0; k < 64; ++k) {
        const float xk = __shfl(xv, k);
        accH = fmaf(xk, sW[k][lane], accH);
        accS = fmaf(xk, sSW[k][lane], accS);
    }
    h[row * 64 + lane] = accH;
    base[row * 64 + lane] = accS + sBias[lane];

    float p = accH * sAttS[lane];
    float q = accH * sAttD[lane];
#pragma unroll
    for (int o = 1; o < 16; o <<= 1) {
        p += __shfl_xor(p, o);
        q += __shfl_xor(q, o);
    }
    if ((lane & 15) == 0) {
        const int head = lane >> 4;
        a_src[row * 4 + head] = p;
        a_dst[row * 4 + head] = q;
    }
}

// ---------------- K2: counting sort by dst -----------------------------------
__global__ __launch_bounds__(BLK) void zero_cnt(int* __restrict__ cnt, int n) {
    int gid = blockIdx.x * BLK + threadIdx.x;
    if (gid < n) cnt[gid] = 0;
}

__global__ __launch_bounds__(BLK) void hist_kernel(
    const int* __restrict__ edst, int* __restrict__ cnt, int n_edges) {
    int gid = blockIdx.x * BLK + threadIdx.x;
    if (gid < n_edges) atomicAdd(&cnt[edst[gid]], 1);
}

// Exclusive scan, 3-phase, 256-elem blocks (Hillis-Steele in LDS)
__global__ __launch_bounds__(BLK) void scan1(
    const int* __restrict__ cnt, int* __restrict__ offs,
    int* __restrict__ bsum, int n) {
    __shared__ int s[BLK];
    const int t = threadIdx.x;
    const int gid = blockIdx.x * BLK + t;
    const int v = (gid < n) ? cnt[gid] : 0;
    s[t] = v;
    __syncthreads();
#pragma unroll
    for (int o = 1; o < BLK; o <<= 1) {
        int u = (t >= o) ? s[t - o] : 0;
        __syncthreads();
        s[t] += u;
        __syncthreads();
    }
    if (gid < n) offs[gid] = s[t] - v;       // exclusive, block-local
    if (t == BLK - 1) bsum[blockIdx.x] = s[t];
}

__global__ __launch_bounds__(BLK) void scan2(int* __restrict__ bsum, int nb) {
    __shared__ int s[BLK];
    const int t = threadIdx.x;
    const int v = (t < nb) ? bsum[t] : 0;
    s[t] = v;
    __syncthreads();
#pragma unroll
    for (int o = 1; o < BLK; o <<= 1) {
        int u = (t >= o) ? s[t - o] : 0;
        __syncthreads();
        s[t] += u;
        __syncthreads();
    }
    if (t < nb) bsum[t] = s[t] - v;          // exclusive
}

__global__ __launch_bounds__(BLK) void scan3(
    int* __restrict__ offs, const int* __restrict__ bsum,
    int* __restrict__ cur, int n, int n_edges) {
    const int gid = blockIdx.x * BLK + threadIdx.x;
    if (gid < n) {
        const int o = offs[gid] + bsum[blockIdx.x];
        offs[gid] = o;
        cur[gid] = o;
    }
    if (gid == 0) offs[n] = n_edges;
}

__global__ __launch_bounds__(BLK) void scatter_kernel(
    const int* __restrict__ esrc, const int* __restrict__ edst,
    int* __restrict__ cur, int* __restrict__ sorted_src, int n_edges) {
    const int gid = blockIdx.x * BLK + threadIdx.x;
    if (gid >= n_edges) return;
    const int d = edst[gid];
    const int pos = atomicAdd(&cur[d], 1);
    sorted_src[pos] = esrc[gid];
}

// ---------------- K3: gather aggregation + finalize --------------------------
// One wave per dst node; lane j owns feature j (head = j>>4). No f32 atomics.
__global__ __launch_bounds__(BLK) void aggregate_kernel(
    const int* __restrict__ sorted_src, const int* __restrict__ offs,
    const float* __restrict__ h, const float* __restrict__ a_src,
    const float* __restrict__ a_dst, float* __restrict__ out, int n_nodes) {
    const int wave = threadIdx.x >> 6, lane = threadIdx.x & 63;
    const int d = blockIdx.x * 4 + wave;
    if (d >= n_nodes) return;
    const int head = lane >> 4;
    const int beg = offs[d], end = offs[d + 1];
    const float ad = a_dst[d * 4 + head];

    // self-loop seed
    float e = a_src[d * 4 + head] + ad;
    e = e > 0.f ? e : 0.2f * e;
    float w = __expf(e);
    float acc = w * h[d * 64 + lane];
    float den = w;

    for (int c = beg; c < end; c += 64) {
        const int sv = (c + lane < end) ? sorted_src[c + lane] : 0;
        const int cn = min(64, end - c);
#pragma unroll 4
        for (int j = 0; j < cn; ++j) {
            const int s = __shfl(sv, j);
            float es = a_src[s * 4 + head] + ad;
            es = es > 0.f ? es : 0.2f * es;
            const float ww = __expf(es);
            acc = fmaf(ww, h[s * 64 + lane], acc);
            den += ww;
        }
    }
    const float v = acc / den + out[d * 64 + lane];
    out[d * 64 + lane] = v > 0.f ? v : 0.1f * expm1f(v);
}

extern "C" void kernel_launch(void* const* d_in, const int* in_sizes, int n_in,
                              void* d_out, int out_size, void* d_ws, size_t ws_size,
                              hipStream_t stream) {
    const float* x         = (const float*)d_in[0];
    const int*   ei_raw    = (const int*)d_in[1];
    const float* W         = (const float*)d_in[2];
    const float* att_src   = (const float*)d_in[3];
    const float* att_dst   = (const float*)d_in[4];
    const float* conv_bias = (const float*)d_in[5];
    const float* skip_W    = (const float*)d_in[6];
    const float* skip_b    = (const float*)d_in[7];

    const int n_nodes = in_sizes[0] / 64;   // 50000
    const int n_edges = in_sizes[1] / 2;    // 800000

    float* ws    = (float*)d_ws;
    float* h     = ws;                                   // N*64 f32
    float* a_src = h + (size_t)n_nodes * 64;             // N*4
    float* a_dst = a_src + (size_t)n_nodes * 4;          // N*4
    int*   e32   = (int*)(a_dst + (size_t)n_nodes * 4);  // 2*E int
    int*   cnt   = e32 + (size_t)2 * n_edges;            // N
    int*   offs  = cnt + n_nodes;                        // N+1
    int*   cur   = offs + n_nodes + 1;                   // N
    int*   bsum  = cur + n_nodes;                        // <=256
    int*   sorted_src = bsum + 256;                      // E
    float* base  = (float*)d_out;                        // N*64 (in-place)

    const int totalE = 2 * n_edges;
    const int nb_n = (n_nodes + BLK - 1) / BLK;          // 196

    convert_edges<<<(totalE + BLK - 1) / BLK, BLK, 0, stream>>>(ei_raw, e32, totalE);

    node_kernel<<<(n_nodes + 3) / 4, BLK, 0, stream>>>(
        x, W, att_src, att_dst, conv_bias, skip_W, skip_b,
        h, base, a_src, a_dst, n_nodes);

    zero_cnt<<<nb_n, BLK, 0, stream>>>(cnt, n_nodes);
    hist_kernel<<<(n_edges + BLK - 1) / BLK, BLK, 0, stream>>>(
        e32 + n_edges, cnt, n_edges);
    scan1<<<nb_n, BLK, 0, stream>>>(cnt, offs, bsum, n_nodes);
    scan2<<<1, BLK, 0, stream>>>(bsum, nb_n);
    scan3<<<nb_n, BLK, 0, stream>>>(offs, bsum, cur, n_nodes, n_edges);
    scatter_kernel<<<(n_edges + BLK - 1) / BLK, BLK, 0, stream>>>(
        e32, e32 + n_edges, cur, sorted_src, n_edges);

    aggregate_kernel<<<(n_nodes + 3) / 4, BLK, 0, stream>>>(
        sorted_src, offs, h, a_src, a_dst, (float*)d_out, n_nodes);
}

// Round 5
// 178.758 us; speedup vs baseline: 1.7348x; 1.3278x over previous
//
#include <hip/hip_runtime.h>
#include <hip/hip_bf16.h>
#include <math.h>

// GAT block: N=50000, E=800000, H_IN=64, HEADS=4, C=16 (F=64 out)
// Round 5 (bisection): MFMA node transform + fused-conversion sort kept;
// aggregate_kernel reverted VERBATIM to round-2's proven per-lane version.

#define BLK 256

typedef __attribute__((ext_vector_type(8))) short short8;
typedef __attribute__((ext_vector_type(4))) float f32x4;

static __device__ __forceinline__ unsigned short f2bf(float f) {
    union { float f; unsigned u; } v; v.f = f;
    return (unsigned short)((v.u + 0x7FFF + ((v.u >> 16) & 1)) >> 16);
}

// ---------------- K0: pack weights + fold attention vectors ------------------
__global__ void prep_weights(const float* __restrict__ W,
                             const float* __restrict__ skipW,
                             const float* __restrict__ conv_bias,
                             const float* __restrict__ skip_b,
                             const float* __restrict__ att_src,
                             const float* __restrict__ att_dst,
                             unsigned short* __restrict__ wfrag,
                             float* __restrict__ bias64,
                             float* __restrict__ watt_s,
                             float* __restrict__ watt_d) {
    const int t = threadIdx.x;
    for (int idx = t; idx < 8192; idx += BLK) {
        const int j = idx & 7;
        const int lane = (idx >> 3) & 63;
        const int kh = (idx >> 9) & 1;
        const int ct = idx >> 10;
        const int k = kh * 32 + (lane >> 4) * 8 + j;
        const int c = ct * 16 + (lane & 15);
        const float v = (c < 64) ? W[k * 64 + c] : skipW[k * 64 + (c - 64)];
        wfrag[idx] = f2bf(v);
    }
    if (t < 64) bias64[t] = conv_bias[t] + skip_b[t];
    {   // t in [0,256): hh = t>>6, k = t&63
        const int hh = t >> 6, k = t & 63;
        float ssum = 0.f, dsum = 0.f;
#pragma unroll
        for (int c = 0; c < 16; ++c) {
            const float wv = W[k * 64 + hh * 16 + c];
            ssum = fmaf(wv, att_src[hh * 16 + c], ssum);
            dsum = fmaf(wv, att_dst[hh * 16 + c], dsum);
        }
        watt_s[hh * 64 + k] = ssum;
        watt_d[hh * 64 + k] = dsum;
    }
}

// ---------------- K1: node transform via MFMA --------------------------------
__global__ __launch_bounds__(BLK) void node_mfma(
    const float* __restrict__ x, const unsigned short* __restrict__ wfrag,
    const float* __restrict__ bias64, const float* __restrict__ watt_s,
    const float* __restrict__ watt_d,
    float* __restrict__ h, float* __restrict__ base,
    float* __restrict__ a_src, float* __restrict__ a_dst, int n) {
    __shared__ unsigned short sfrag[4 * 64 * 16];  // [wave][lane][kh*8+j], 8KB
    __shared__ float swatt[512];                   // watt_s | watt_d
    const int t = threadIdx.x;
    const int rowBase = blockIdx.x * 64;

    swatt[t] = watt_s[t];
    swatt[256 + t] = watt_d[t];

    const int r = t >> 2;
    const int c0 = (t & 3) << 4;
    const int grow = rowBase + r;
    float vals[16];
    if (grow < n) {
        const float4* xp = reinterpret_cast<const float4*>(x + (size_t)grow * 64 + c0);
        float4 a0 = xp[0], a1 = xp[1], a2 = xp[2], a3 = xp[3];
        vals[0]=a0.x; vals[1]=a0.y; vals[2]=a0.z; vals[3]=a0.w;
        vals[4]=a1.x; vals[5]=a1.y; vals[6]=a1.z; vals[7]=a1.w;
        vals[8]=a2.x; vals[9]=a2.y; vals[10]=a2.z; vals[11]=a2.w;
        vals[12]=a3.x; vals[13]=a3.y; vals[14]=a3.z; vals[15]=a3.w;
    } else {
#pragma unroll
        for (int i = 0; i < 16; ++i) vals[i] = 0.f;
    }

    // write the two bf16 k-octets straight into A-fragment slots
    {
        const int r15 = r & 15, wv = r >> 4;
#pragma unroll
        for (int oo = 0; oo < 2; ++oo) {
            const int oct = (t & 3) * 2 + oo;       // 0..7
            const int kh = oct >> 2, rg = oct & 3;
            const int lane = rg * 16 + r15;
            short8 p;
#pragma unroll
            for (int i = 0; i < 8; ++i) p[i] = (short)f2bf(vals[oo * 8 + i]);
            *reinterpret_cast<short8*>(&sfrag[((wv * 64 + lane) * 2 + kh) * 8]) = p;
        }
    }
    __syncthreads();

    // ---- f32 attention logits: a[grow][hh] = sum_k x[grow][k]*watt[hh][k]
    {
#pragma unroll
        for (int hh = 0; hh < 4; ++hh) {
            float s = 0.f, dd = 0.f;
#pragma unroll
            for (int i = 0; i < 16; ++i) {
                s  = fmaf(vals[i], swatt[hh * 64 + c0 + i], s);
                dd = fmaf(vals[i], swatt[256 + hh * 64 + c0 + i], dd);
            }
            s  += __shfl_xor(s, 1);  s  += __shfl_xor(s, 2);
            dd += __shfl_xor(dd, 1); dd += __shfl_xor(dd, 2);
            if ((t & 3) == 0 && grow < n) {
                a_src[grow * 4 + hh] = s;
                a_dst[grow * 4 + hh] = dd;
            }
        }
    }

    // ---- MFMA: 16 rows/wave x 128 cols
    const int wave = t >> 6, lane = t & 63;
    const int q = lane & 15, rg = lane >> 4;

    short8 bfr[8][2];
#pragma unroll
    for (int ct = 0; ct < 8; ++ct)
#pragma unroll
        for (int kh = 0; kh < 2; ++kh)
            bfr[ct][kh] = *reinterpret_cast<const short8*>(
                wfrag + (size_t)((ct * 2 + kh) * 64 + lane) * 8);

    short8 afr[2];
#pragma unroll
    for (int kh = 0; kh < 2; ++kh)
        afr[kh] = *reinterpret_cast<const short8*>(
            &sfrag[((wave * 64 + lane) * 2 + kh) * 8]);

    f32x4 acc[8];
#pragma unroll
    for (int i = 0; i < 8; ++i) { acc[i][0]=0.f; acc[i][1]=0.f; acc[i][2]=0.f; acc[i][3]=0.f; }
#pragma unroll
    for (int ct = 0; ct < 8; ++ct)
#pragma unroll
        for (int kh = 0; kh < 2; ++kh)
            acc[ct] = __builtin_amdgcn_mfma_f32_16x16x32_bf16(
                afr[kh], bfr[ct][kh], acc[ct], 0, 0, 0);

    float biasv[4];
#pragma unroll
    for (int i = 0; i < 4; ++i) biasv[i] = bias64[i * 16 + q];

    // h (ct 0..3): D row = rg*4+j, col = ct*16+q
#pragma unroll
    for (int ct = 0; ct < 4; ++ct)
#pragma unroll
        for (int j = 0; j < 4; ++j) {
            const int gr = rowBase + wave * 16 + rg * 4 + j;
            if (gr < n) h[(size_t)gr * 64 + ct * 16 + q] = acc[ct][j];
        }
    // base (ct 4..7) + bias -> d_out
#pragma unroll
    for (int ct = 4; ct < 8; ++ct)
#pragma unroll
        for (int j = 0; j < 4; ++j) {
            const int gr = rowBase + wave * 16 + rg * 4 + j;
            if (gr < n)
                base[(size_t)gr * 64 + (ct - 4) * 16 + q] = acc[ct][j] + biasv[ct - 4];
        }
}

// ---------------- K2: counting sort by dst (conversion fused) ----------------
__global__ __launch_bounds__(BLK) void zero_cnt(int* __restrict__ cnt, int n) {
    int gid = blockIdx.x * BLK + threadIdx.x;
    if (gid < n) cnt[gid] = 0;
}

__global__ __launch_bounds__(BLK) void hist_kernel(
    const int* __restrict__ ei_raw, int* __restrict__ cnt, int n_edges) {
    __shared__ int s_is64;
    if (threadIdx.x == 0) {
        int all0 = 1;
        for (int i = 1; i < 128; i += 2) all0 &= (ei_raw[i] == 0);
        s_is64 = all0;
    }
    __syncthreads();
    const int gid = blockIdx.x * BLK + threadIdx.x;
    if (gid >= n_edges) return;
    const int d = s_is64 ? (int)((const long long*)ei_raw)[n_edges + gid]
                         : ei_raw[n_edges + gid];
    atomicAdd(&cnt[d], 1);
}

__global__ __launch_bounds__(BLK) void scan1(
    const int* __restrict__ cnt, int* __restrict__ offs,
    int* __restrict__ bsum, int n) {
    __shared__ int s[BLK];
    const int t = threadIdx.x;
    const int gid = blockIdx.x * BLK + t;
    const int v = (gid < n) ? cnt[gid] : 0;
    s[t] = v;
    __syncthreads();
#pragma unroll
    for (int o = 1; o < BLK; o <<= 1) {
        int u = (t >= o) ? s[t - o] : 0;
        __syncthreads();
        s[t] += u;
        __syncthreads();
    }
    if (gid < n) offs[gid] = s[t] - v;
    if (t == BLK - 1) bsum[blockIdx.x] = s[t];
}

__global__ __launch_bounds__(BLK) void scan2(int* __restrict__ bsum, int nb) {
    __shared__ int s[BLK];
    const int t = threadIdx.x;
    const int v = (t < nb) ? bsum[t] : 0;
    s[t] = v;
    __syncthreads();
#pragma unroll
    for (int o = 1; o < BLK; o <<= 1) {
        int u = (t >= o) ? s[t - o] : 0;
        __syncthreads();
        s[t] += u;
        __syncthreads();
    }
    if (t < nb) bsum[t] = s[t] - v;
}

__global__ __launch_bounds__(BLK) void scan3(
    int* __restrict__ offs, const int* __restrict__ bsum,
    int* __restrict__ cur, int n, int n_edges) {
    const int gid = blockIdx.x * BLK + threadIdx.x;
    if (gid < n) {
        const int o = offs[gid] + bsum[blockIdx.x];
        offs[gid] = o;
        cur[gid] = o;
    }
    if (gid == 0) offs[n] = n_edges;
}

__global__ __launch_bounds__(BLK) void scatter_kernel(
    const int* __restrict__ ei_raw, int* __restrict__ cur,
    int* __restrict__ sorted_src, int n_edges) {
    __shared__ int s_is64;
    if (threadIdx.x == 0) {
        int all0 = 1;
        for (int i = 1; i < 128; i += 2) all0 &= (ei_raw[i] == 0);
        s_is64 = all0;
    }
    __syncthreads();
    const int gid = blockIdx.x * BLK + threadIdx.x;
    if (gid >= n_edges) return;
    int s, d;
    if (s_is64) {
        const long long* e64 = (const long long*)ei_raw;
        s = (int)e64[gid];
        d = (int)e64[n_edges + gid];
    } else {
        s = ei_raw[gid];
        d = ei_raw[n_edges + gid];
    }
    const int pos = atomicAdd(&cur[d], 1);
    sorted_src[pos] = s;
}

// ---------------- K3: gather aggregation + finalize (round-2 verbatim) -------
// One wave per dst node; lane j owns feature j (head = j>>4). No f32 atomics.
__global__ __launch_bounds__(BLK) void aggregate_kernel(
    const int* __restrict__ sorted_src, const int* __restrict__ offs,
    const float* __restrict__ h, const float* __restrict__ a_src,
    const float* __restrict__ a_dst, float* __restrict__ out, int n_nodes) {
    const int wave = threadIdx.x >> 6, lane = threadIdx.x & 63;
    const int d = blockIdx.x * 4 + wave;
    if (d >= n_nodes) return;
    const int head = lane >> 4;
    const int beg = offs[d], end = offs[d + 1];
    const float ad = a_dst[d * 4 + head];

    // self-loop seed
    float e = a_src[d * 4 + head] + ad;
    e = e > 0.f ? e : 0.2f * e;
    float w = __expf(e);
    float acc = w * h[d * 64 + lane];
    float den = w;

    for (int c = beg; c < end; c += 64) {
        const int sv = (c + lane < end) ? sorted_src[c + lane] : 0;
        const int cn = min(64, end - c);
#pragma unroll 4
        for (int j = 0; j < cn; ++j) {
            const int s = __shfl(sv, j);
            float es = a_src[s * 4 + head] + ad;
            es = es > 0.f ? es : 0.2f * es;
            const float ww = __expf(es);
            acc = fmaf(ww, h[s * 64 + lane], acc);
            den += ww;
        }
    }
    const float v = acc / den + out[d * 64 + lane];
    out[d * 64 + lane] = v > 0.f ? v : 0.1f * expm1f(v);
}

extern "C" void kernel_launch(void* const* d_in, const int* in_sizes, int n_in,
                              void* d_out, int out_size, void* d_ws, size_t ws_size,
                              hipStream_t stream) {
    const float* x         = (const float*)d_in[0];
    const int*   ei_raw    = (const int*)d_in[1];
    const float* W         = (const float*)d_in[2];
    const float* att_src   = (const float*)d_in[3];
    const float* att_dst   = (const float*)d_in[4];
    const float* conv_bias = (const float*)d_in[5];
    const float* skip_W    = (const float*)d_in[6];
    const float* skip_b    = (const float*)d_in[7];

    const int n_nodes = in_sizes[0] / 64;   // 50000
    const int n_edges = in_sizes[1] / 2;    // 800000

    float* ws = (float*)d_ws;
    unsigned short* wfrag = (unsigned short*)ws;          // 8192 u16 (offset 0)
    float* bias64 = ws + 4096;                            // 64
    float* watt_s = bias64 + 64;                          // 256
    float* watt_d = watt_s + 256;                         // 256
    float* h      = watt_d + 256;                         // N*64 (16B-aligned)
    float* a_src  = h + (size_t)n_nodes * 64;             // N*4
    float* a_dst  = a_src + (size_t)n_nodes * 4;          // N*4
    int*   cnt    = (int*)(a_dst + (size_t)n_nodes * 4);  // N
    int*   offs   = cnt + n_nodes;                        // N+1
    int*   cur    = offs + n_nodes + 1;                   // N
    int*   bsum   = cur + n_nodes;                        // 256
    int*   sorted_src = bsum + 256;                       // E
    float* base   = (float*)d_out;

    const int nb_n = (n_nodes + BLK - 1) / BLK;           // 196
    const int nb_e = (n_edges + BLK - 1) / BLK;           // 3125

    prep_weights<<<1, BLK, 0, stream>>>(W, skip_W, conv_bias, skip_b,
                                        att_src, att_dst, wfrag, bias64,
                                        watt_s, watt_d);
    zero_cnt<<<nb_n, BLK, 0, stream>>>(cnt, n_nodes);
    hist_kernel<<<nb_e, BLK, 0, stream>>>(ei_raw, cnt, n_edges);

    node_mfma<<<(n_nodes + 63) / 64, BLK, 0, stream>>>(
        x, wfrag, bias64, watt_s, watt_d, h, base, a_src, a_dst, n_nodes);

    scan1<<<nb_n, BLK, 0, stream>>>(cnt, offs, bsum, n_nodes);
    scan2<<<1, BLK, 0, stream>>>(bsum, nb_n);
    scan3<<<nb_n, BLK, 0, stream>>>(offs, bsum, cur, n_nodes, n_edges);
    scatter_kernel<<<nb_e, BLK, 0, stream>>>(ei_raw, cur, sorted_src, n_edges);

    aggregate_kernel<<<(n_nodes + 3) / 4, BLK, 0, stream>>>(
        sorted_src, offs, h, a_src, a_dst, (float*)d_out, n_nodes);
}

// Round 6
// 166.600 us; speedup vs baseline: 1.8614x; 1.0730x over previous
//
#include <hip/hip_runtime.h>
#include <hip/hip_bf16.h>
#include <math.h>

// GAT block: N=50000, E=800000, H_IN=64, HEADS=4, C=16 (F=64 out)
// Round 6: aggregate de-latencied — h stored bf16 (half gather bytes),
// per-edge softmax weights precomputed in scatter (kills a_src->exp chain
// in the inner loop). zero_cnt fused into prep.

#define BLK 256

typedef __attribute__((ext_vector_type(8))) short short8;
typedef __attribute__((ext_vector_type(4))) float f32x4;

static __device__ __forceinline__ unsigned short f2bf(float f) {
    union { float f; unsigned u; } v; v.f = f;
    return (unsigned short)((v.u + 0x7FFF + ((v.u >> 16) & 1)) >> 16);
}
static __device__ __forceinline__ float bf2f(unsigned short u) {
    union { unsigned u; float f; } v; v.u = ((unsigned)u) << 16;
    return v.f;
}

// ---------------- K0: pack weights + fold att vectors + zero cnt -------------
__global__ void prep_weights(const float* __restrict__ W,
                             const float* __restrict__ skipW,
                             const float* __restrict__ conv_bias,
                             const float* __restrict__ skip_b,
                             const float* __restrict__ att_src,
                             const float* __restrict__ att_dst,
                             unsigned short* __restrict__ wfrag,
                             float* __restrict__ bias64,
                             float* __restrict__ watt_s,
                             float* __restrict__ watt_d,
                             int* __restrict__ cnt, int n_nodes) {
    const int t = threadIdx.x;
    if (blockIdx.x != 0) {   // blocks 1.. zero the histogram
        const int gid = (blockIdx.x - 1) * BLK + t;
        if (gid < n_nodes) cnt[gid] = 0;
        return;
    }
    for (int idx = t; idx < 8192; idx += BLK) {
        const int j = idx & 7;
        const int lane = (idx >> 3) & 63;
        const int kh = (idx >> 9) & 1;
        const int ct = idx >> 10;
        const int k = kh * 32 + (lane >> 4) * 8 + j;
        const int c = ct * 16 + (lane & 15);
        const float v = (c < 64) ? W[k * 64 + c] : skipW[k * 64 + (c - 64)];
        wfrag[idx] = f2bf(v);
    }
    if (t < 64) bias64[t] = conv_bias[t] + skip_b[t];
    {   // t in [0,256): hh = t>>6, k = t&63
        const int hh = t >> 6, k = t & 63;
        float ssum = 0.f, dsum = 0.f;
#pragma unroll
        for (int c = 0; c < 16; ++c) {
            const float wv = W[k * 64 + hh * 16 + c];
            ssum = fmaf(wv, att_src[hh * 16 + c], ssum);
            dsum = fmaf(wv, att_dst[hh * 16 + c], dsum);
        }
        watt_s[hh * 64 + k] = ssum;
        watt_d[hh * 64 + k] = dsum;
    }
}

// ---------------- K1: node transform via MFMA --------------------------------
__global__ __launch_bounds__(BLK) void node_mfma(
    const float* __restrict__ x, const unsigned short* __restrict__ wfrag,
    const float* __restrict__ bias64, const float* __restrict__ watt_s,
    const float* __restrict__ watt_d,
    unsigned short* __restrict__ h16, float* __restrict__ base,
    float* __restrict__ a_src, float* __restrict__ a_dst, int n) {
    __shared__ unsigned short sfrag[4 * 64 * 16];  // [wave][lane][kh*8+j], 8KB
    __shared__ float swatt[512];                   // watt_s | watt_d
    const int t = threadIdx.x;
    const int rowBase = blockIdx.x * 64;

    swatt[t] = watt_s[t];
    swatt[256 + t] = watt_d[t];

    const int r = t >> 2;
    const int c0 = (t & 3) << 4;
    const int grow = rowBase + r;
    float vals[16];
    if (grow < n) {
        const float4* xp = reinterpret_cast<const float4*>(x + (size_t)grow * 64 + c0);
        float4 a0 = xp[0], a1 = xp[1], a2 = xp[2], a3 = xp[3];
        vals[0]=a0.x; vals[1]=a0.y; vals[2]=a0.z; vals[3]=a0.w;
        vals[4]=a1.x; vals[5]=a1.y; vals[6]=a1.z; vals[7]=a1.w;
        vals[8]=a2.x; vals[9]=a2.y; vals[10]=a2.z; vals[11]=a2.w;
        vals[12]=a3.x; vals[13]=a3.y; vals[14]=a3.z; vals[15]=a3.w;
    } else {
#pragma unroll
        for (int i = 0; i < 16; ++i) vals[i] = 0.f;
    }

    // write the two bf16 k-octets straight into A-fragment slots
    {
        const int r15 = r & 15, wv = r >> 4;
#pragma unroll
        for (int oo = 0; oo < 2; ++oo) {
            const int oct = (t & 3) * 2 + oo;       // 0..7
            const int kh = oct >> 2, rg = oct & 3;
            const int lane = rg * 16 + r15;
            short8 p;
#pragma unroll
            for (int i = 0; i < 8; ++i) p[i] = (short)f2bf(vals[oo * 8 + i]);
            *reinterpret_cast<short8*>(&sfrag[((wv * 64 + lane) * 2 + kh) * 8]) = p;
        }
    }
    __syncthreads();

    // ---- f32 attention logits
    {
#pragma unroll
        for (int hh = 0; hh < 4; ++hh) {
            float s = 0.f, dd = 0.f;
#pragma unroll
            for (int i = 0; i < 16; ++i) {
                s  = fmaf(vals[i], swatt[hh * 64 + c0 + i], s);
                dd = fmaf(vals[i], swatt[256 + hh * 64 + c0 + i], dd);
            }
            s  += __shfl_xor(s, 1);  s  += __shfl_xor(s, 2);
            dd += __shfl_xor(dd, 1); dd += __shfl_xor(dd, 2);
            if ((t & 3) == 0 && grow < n) {
                a_src[grow * 4 + hh] = s;
                a_dst[grow * 4 + hh] = dd;
            }
        }
    }

    // ---- MFMA: 16 rows/wave x 128 cols
    const int wave = t >> 6, lane = t & 63;
    const int q = lane & 15, rg = lane >> 4;

    short8 bfr[8][2];
#pragma unroll
    for (int ct = 0; ct < 8; ++ct)
#pragma unroll
        for (int kh = 0; kh < 2; ++kh)
            bfr[ct][kh] = *reinterpret_cast<const short8*>(
                wfrag + (size_t)((ct * 2 + kh) * 64 + lane) * 8);

    short8 afr[2];
#pragma unroll
    for (int kh = 0; kh < 2; ++kh)
        afr[kh] = *reinterpret_cast<const short8*>(
            &sfrag[((wave * 64 + lane) * 2 + kh) * 8]);

    f32x4 acc[8];
#pragma unroll
    for (int i = 0; i < 8; ++i) { acc[i][0]=0.f; acc[i][1]=0.f; acc[i][2]=0.f; acc[i][3]=0.f; }
#pragma unroll
    for (int ct = 0; ct < 8; ++ct)
#pragma unroll
        for (int kh = 0; kh < 2; ++kh)
            acc[ct] = __builtin_amdgcn_mfma_f32_16x16x32_bf16(
                afr[kh], bfr[ct][kh], acc[ct], 0, 0, 0);

    float biasv[4];
#pragma unroll
    for (int i = 0; i < 4; ++i) biasv[i] = bias64[i * 16 + q];

    // h (ct 0..3) -> bf16
#pragma unroll
    for (int ct = 0; ct < 4; ++ct)
#pragma unroll
        for (int j = 0; j < 4; ++j) {
            const int gr = rowBase + wave * 16 + rg * 4 + j;
            if (gr < n) h16[(size_t)gr * 64 + ct * 16 + q] = f2bf(acc[ct][j]);
        }
    // base (ct 4..7) + bias -> d_out
#pragma unroll
    for (int ct = 4; ct < 8; ++ct)
#pragma unroll
        for (int j = 0; j < 4; ++j) {
            const int gr = rowBase + wave * 16 + rg * 4 + j;
            if (gr < n)
                base[(size_t)gr * 64 + (ct - 4) * 16 + q] = acc[ct][j] + biasv[ct - 4];
        }
}

// ---------------- K2: counting sort by dst (conversion fused) ----------------
__global__ __launch_bounds__(BLK) void hist_kernel(
    const int* __restrict__ ei_raw, int* __restrict__ cnt, int n_edges) {
    __shared__ int s_is64;
    if (threadIdx.x == 0) {
        int all0 = 1;
        for (int i = 1; i < 128; i += 2) all0 &= (ei_raw[i] == 0);
        s_is64 = all0;
    }
    __syncthreads();
    const int gid = blockIdx.x * BLK + threadIdx.x;
    if (gid >= n_edges) return;
    const int d = s_is64 ? (int)((const long long*)ei_raw)[n_edges + gid]
                         : ei_raw[n_edges + gid];
    atomicAdd(&cnt[d], 1);
}

__global__ __launch_bounds__(BLK) void scan1(
    const int* __restrict__ cnt, int* __restrict__ offs,
    int* __restrict__ bsum, int n) {
    __shared__ int s[BLK];
    const int t = threadIdx.x;
    const int gid = blockIdx.x * BLK + t;
    const int v = (gid < n) ? cnt[gid] : 0;
    s[t] = v;
    __syncthreads();
#pragma unroll
    for (int o = 1; o < BLK; o <<= 1) {
        int u = (t >= o) ? s[t - o] : 0;
        __syncthreads();
        s[t] += u;
        __syncthreads();
    }
    if (gid < n) offs[gid] = s[t] - v;
    if (t == BLK - 1) bsum[blockIdx.x] = s[t];
}

__global__ __launch_bounds__(BLK) void scan2(int* __restrict__ bsum, int nb) {
    __shared__ int s[BLK];
    const int t = threadIdx.x;
    const int v = (t < nb) ? bsum[t] : 0;
    s[t] = v;
    __syncthreads();
#pragma unroll
    for (int o = 1; o < BLK; o <<= 1) {
        int u = (t >= o) ? s[t - o] : 0;
        __syncthreads();
        s[t] += u;
        __syncthreads();
    }
    if (t < nb) bsum[t] = s[t] - v;
}

__global__ __launch_bounds__(BLK) void scan3(
    int* __restrict__ offs, const int* __restrict__ bsum,
    int* __restrict__ cur, int n, int n_edges) {
    const int gid = blockIdx.x * BLK + threadIdx.x;
    if (gid < n) {
        const int o = offs[gid] + bsum[blockIdx.x];
        offs[gid] = o;
        cur[gid] = o;
    }
    if (gid == 0) offs[n] = n_edges;
}

// Scatter: place src index AND precomputed per-head bf16 softmax weights at
// the sorted position. Kills the a_src-gather->exp chain in the aggregate.
__global__ __launch_bounds__(BLK) void scatter_kernel(
    const int* __restrict__ ei_raw, const float* __restrict__ a_src,
    const float* __restrict__ a_dst, int* __restrict__ cur,
    int* __restrict__ sorted_src, unsigned short* __restrict__ sorted_wh,
    int n_edges) {
    __shared__ int s_is64;
    if (threadIdx.x == 0) {
        int all0 = 1;
        for (int i = 1; i < 128; i += 2) all0 &= (ei_raw[i] == 0);
        s_is64 = all0;
    }
    __syncthreads();
    const int gid = blockIdx.x * BLK + threadIdx.x;
    if (gid >= n_edges) return;
    int s, d;
    if (s_is64) {
        const long long* e64 = (const long long*)ei_raw;
        s = (int)e64[gid];
        d = (int)e64[n_edges + gid];
    } else {
        s = ei_raw[gid];
        d = ei_raw[n_edges + gid];
    }
    const int pos = atomicAdd(&cur[d], 1);
    sorted_src[pos] = s;

    const float4 as = *reinterpret_cast<const float4*>(a_src + (size_t)s * 4);
    const float4 adv = *reinterpret_cast<const float4*>(a_dst + (size_t)d * 4);
    float e0 = as.x + adv.x, e1 = as.y + adv.y, e2 = as.z + adv.z, e3 = as.w + adv.w;
    e0 = e0 > 0.f ? e0 : 0.2f * e0;
    e1 = e1 > 0.f ? e1 : 0.2f * e1;
    e2 = e2 > 0.f ? e2 : 0.2f * e2;
    e3 = e3 > 0.f ? e3 : 0.2f * e3;
    uint2 wp;
    wp.x = (unsigned)f2bf(__expf(e0)) | ((unsigned)f2bf(__expf(e1)) << 16);
    wp.y = (unsigned)f2bf(__expf(e2)) | ((unsigned)f2bf(__expf(e3)) << 16);
    *reinterpret_cast<uint2*>(&sorted_wh[(size_t)pos * 4]) = wp;
}

// ---------------- K3: gather aggregation + finalize --------------------------
// One wave per dst node; lane j owns feature j (head = j>>4).
// Inner loop: sequential bf16 weight read + bf16 h-row gather + fma.
__global__ __launch_bounds__(BLK) void aggregate_kernel(
    const int* __restrict__ sorted_src, const unsigned short* __restrict__ sorted_wh,
    const int* __restrict__ offs, const unsigned short* __restrict__ h16,
    const float* __restrict__ a_src, const float* __restrict__ a_dst,
    float* __restrict__ out, int n_nodes) {
    const int wave = threadIdx.x >> 6, lane = threadIdx.x & 63;
    const int d = blockIdx.x * 4 + wave;
    if (d >= n_nodes) return;
    const int head = lane >> 4;
    const int beg = offs[d], end = offs[d + 1];

    // self-loop seed (exact f32 logits)
    float e = a_src[d * 4 + head] + a_dst[d * 4 + head];
    e = e > 0.f ? e : 0.2f * e;
    float w = __expf(e);
    float acc = w * bf2f(h16[(size_t)d * 64 + lane]);
    float den = w;

    for (int c = beg; c < end; c += 64) {
        const int sv = (c + lane < end) ? sorted_src[c + lane] : 0;
        const int cn = min(64, end - c);
#pragma unroll 4
        for (int j = 0; j < cn; ++j) {
            const int s = __shfl(sv, j);
            const float ww = bf2f(sorted_wh[(size_t)(c + j) * 4 + head]);
            acc = fmaf(ww, bf2f(h16[(size_t)s * 64 + lane]), acc);
            den += ww;
        }
    }
    const float v = acc / den + out[(size_t)d * 64 + lane];
    out[(size_t)d * 64 + lane] = v > 0.f ? v : 0.1f * expm1f(v);
}

extern "C" void kernel_launch(void* const* d_in, const int* in_sizes, int n_in,
                              void* d_out, int out_size, void* d_ws, size_t ws_size,
                              hipStream_t stream) {
    const float* x         = (const float*)d_in[0];
    const int*   ei_raw    = (const int*)d_in[1];
    const float* W         = (const float*)d_in[2];
    const float* att_src   = (const float*)d_in[3];
    const float* att_dst   = (const float*)d_in[4];
    const float* conv_bias = (const float*)d_in[5];
    const float* skip_W    = (const float*)d_in[6];
    const float* skip_b    = (const float*)d_in[7];

    const int n_nodes = in_sizes[0] / 64;   // 50000
    const int n_edges = in_sizes[1] / 2;    // 800000

    float* ws = (float*)d_ws;
    unsigned short* wfrag = (unsigned short*)ws;          // 8192 u16 (offset 0)
    float* bias64 = ws + 4096;                            // 64
    float* watt_s = bias64 + 64;                          // 256
    float* watt_d = watt_s + 256;                         // 256
    unsigned short* h16 = (unsigned short*)(watt_d + 256);// N*64 u16
    float* a_src  = (float*)(h16 + (size_t)n_nodes * 64); // N*4
    float* a_dst  = a_src + (size_t)n_nodes * 4;          // N*4
    int*   cnt    = (int*)(a_dst + (size_t)n_nodes * 4);  // N
    int*   offs   = cnt + n_nodes;                        // N+1
    int*   cur    = offs + n_nodes + 1;                   // N
    int*   bsum   = cur + n_nodes;                        // 256
    int*   sorted_src = bsum + 256;                       // E
    unsigned short* sorted_wh = (unsigned short*)(sorted_src + n_edges); // E*4 u16
    float* base   = (float*)d_out;

    const int nb_n = (n_nodes + BLK - 1) / BLK;           // 196
    const int nb_e = (n_edges + BLK - 1) / BLK;           // 3125

    prep_weights<<<nb_n + 1, BLK, 0, stream>>>(W, skip_W, conv_bias, skip_b,
                                               att_src, att_dst, wfrag, bias64,
                                               watt_s, watt_d, cnt, n_nodes);
    hist_kernel<<<nb_e, BLK, 0, stream>>>(ei_raw, cnt, n_edges);

    node_mfma<<<(n_nodes + 63) / 64, BLK, 0, stream>>>(
        x, wfrag, bias64, watt_s, watt_d, h16, base, a_src, a_dst, n_nodes);

    scan1<<<nb_n, BLK, 0, stream>>>(cnt, offs, bsum, n_nodes);
    scan2<<<1, BLK, 0, stream>>>(bsum, nb_n);
    scan3<<<nb_n, BLK, 0, stream>>>(offs, bsum, cur, n_nodes, n_edges);
    scatter_kernel<<<nb_e, BLK, 0, stream>>>(ei_raw, a_src, a_dst, cur,
                                             sorted_src, sorted_wh, n_edges);

    aggregate_kernel<<<(n_nodes + 3) / 4, BLK, 0, stream>>>(
        sorted_src, sorted_wh, offs, h16, a_src, a_dst, (float*)d_out, n_nodes);
}

// Round 8
// 149.384 us; speedup vs baseline: 2.0759x; 1.1152x over previous
//
#include <hip/hip_runtime.h>
#include <hip/hip_bf16.h>
#include <math.h>

// GAT block: N=50000, E=800000, H_IN=64, HEADS=4, C=16 (F=64 out)
// Round 8: aggregate = round-6 per-feature sequential arithmetic, but
// shfl-free (uniform 16B payload read per edge), h and w stored f16
// (accuracy margin), scan2 fused into scan3 (7 launches total).

#define BLK 256

typedef __attribute__((ext_vector_type(8))) short short8;
typedef __attribute__((ext_vector_type(4))) float f32x4;

static __device__ __forceinline__ unsigned short f2bf(float f) {
    union { float f; unsigned u; } v; v.f = f;
    return (unsigned short)((v.u + 0x7FFF + ((v.u >> 16) & 1)) >> 16);
}
static __device__ __forceinline__ unsigned short f2fh(float f) {
    union { _Float16 h; unsigned short u; } v; v.h = (_Float16)f; return v.u;
}
static __device__ __forceinline__ float fh2f(unsigned short u) {
    union { _Float16 h; unsigned short u; } v; v.u = u; return (float)v.h;
}

// ---------------- K0: pack weights + fold att vectors + zero cnt -------------
__global__ void prep_weights(const float* __restrict__ W,
                             const float* __restrict__ skipW,
                             const float* __restrict__ conv_bias,
                             const float* __restrict__ skip_b,
                             const float* __restrict__ att_src,
                             const float* __restrict__ att_dst,
                             unsigned short* __restrict__ wfrag,
                             float* __restrict__ bias64,
                             float* __restrict__ watt_s,
                             float* __restrict__ watt_d,
                             int* __restrict__ cnt, int n_nodes) {
    const int t = threadIdx.x;
    if (blockIdx.x != 0) {   // blocks 1.. zero the histogram
        const int gid = (blockIdx.x - 1) * BLK + t;
        if (gid < n_nodes) cnt[gid] = 0;
        return;
    }
    for (int idx = t; idx < 8192; idx += BLK) {
        const int j = idx & 7;
        const int lane = (idx >> 3) & 63;
        const int kh = (idx >> 9) & 1;
        const int ct = idx >> 10;
        const int k = kh * 32 + (lane >> 4) * 8 + j;
        const int c = ct * 16 + (lane & 15);
        const float v = (c < 64) ? W[k * 64 + c] : skipW[k * 64 + (c - 64)];
        wfrag[idx] = f2bf(v);
    }
    if (t < 64) bias64[t] = conv_bias[t] + skip_b[t];
    {   // t in [0,256): hh = t>>6, k = t&63
        const int hh = t >> 6, k = t & 63;
        float ssum = 0.f, dsum = 0.f;
#pragma unroll
        for (int c = 0; c < 16; ++c) {
            const float wv = W[k * 64 + hh * 16 + c];
            ssum = fmaf(wv, att_src[hh * 16 + c], ssum);
            dsum = fmaf(wv, att_dst[hh * 16 + c], dsum);
        }
        watt_s[hh * 64 + k] = ssum;
        watt_d[hh * 64 + k] = dsum;
    }
}

// ---------------- K1: node transform via MFMA --------------------------------
__global__ __launch_bounds__(BLK) void node_mfma(
    const float* __restrict__ x, const unsigned short* __restrict__ wfrag,
    const float* __restrict__ bias64, const float* __restrict__ watt_s,
    const float* __restrict__ watt_d,
    unsigned short* __restrict__ h16, float* __restrict__ base,
    float* __restrict__ a_src, float* __restrict__ a_dst, int n) {
    __shared__ unsigned short sfrag[4 * 64 * 16];  // [wave][lane][kh*8+j], 8KB
    __shared__ float swatt[512];                   // watt_s | watt_d
    const int t = threadIdx.x;
    const int rowBase = blockIdx.x * 64;

    swatt[t] = watt_s[t];
    swatt[256 + t] = watt_d[t];

    const int r = t >> 2;
    const int c0 = (t & 3) << 4;
    const int grow = rowBase + r;
    float vals[16];
    if (grow < n) {
        const float4* xp = reinterpret_cast<const float4*>(x + (size_t)grow * 64 + c0);
        float4 a0 = xp[0], a1 = xp[1], a2 = xp[2], a3 = xp[3];
        vals[0]=a0.x; vals[1]=a0.y; vals[2]=a0.z; vals[3]=a0.w;
        vals[4]=a1.x; vals[5]=a1.y; vals[6]=a1.z; vals[7]=a1.w;
        vals[8]=a2.x; vals[9]=a2.y; vals[10]=a2.z; vals[11]=a2.w;
        vals[12]=a3.x; vals[13]=a3.y; vals[14]=a3.z; vals[15]=a3.w;
    } else {
#pragma unroll
        for (int i = 0; i < 16; ++i) vals[i] = 0.f;
    }

    // write the two bf16 k-octets straight into A-fragment slots
    {
        const int r15 = r & 15, wv = r >> 4;
#pragma unroll
        for (int oo = 0; oo < 2; ++oo) {
            const int oct = (t & 3) * 2 + oo;       // 0..7
            const int kh = oct >> 2, rg = oct & 3;
            const int lane = rg * 16 + r15;
            short8 p;
#pragma unroll
            for (int i = 0; i < 8; ++i) p[i] = (short)f2bf(vals[oo * 8 + i]);
            *reinterpret_cast<short8*>(&sfrag[((wv * 64 + lane) * 2 + kh) * 8]) = p;
        }
    }
    __syncthreads();

    // ---- f32 attention logits
    {
#pragma unroll
        for (int hh = 0; hh < 4; ++hh) {
            float s = 0.f, dd = 0.f;
#pragma unroll
            for (int i = 0; i < 16; ++i) {
                s  = fmaf(vals[i], swatt[hh * 64 + c0 + i], s);
                dd = fmaf(vals[i], swatt[256 + hh * 64 + c0 + i], dd);
            }
            s  += __shfl_xor(s, 1);  s  += __shfl_xor(s, 2);
            dd += __shfl_xor(dd, 1); dd += __shfl_xor(dd, 2);
            if ((t & 3) == 0 && grow < n) {
                a_src[grow * 4 + hh] = s;
                a_dst[grow * 4 + hh] = dd;
            }
        }
    }

    // ---- MFMA: 16 rows/wave x 128 cols
    const int wave = t >> 6, lane = t & 63;
    const int q = lane & 15, rg = lane >> 4;

    short8 bfr[8][2];
#pragma unroll
    for (int ct = 0; ct < 8; ++ct)
#pragma unroll
        for (int kh = 0; kh < 2; ++kh)
            bfr[ct][kh] = *reinterpret_cast<const short8*>(
                wfrag + (size_t)((ct * 2 + kh) * 64 + lane) * 8);

    short8 afr[2];
#pragma unroll
    for (int kh = 0; kh < 2; ++kh)
        afr[kh] = *reinterpret_cast<const short8*>(
            &sfrag[((wave * 64 + lane) * 2 + kh) * 8]);

    f32x4 acc[8];
#pragma unroll
    for (int i = 0; i < 8; ++i) { acc[i][0]=0.f; acc[i][1]=0.f; acc[i][2]=0.f; acc[i][3]=0.f; }
#pragma unroll
    for (int ct = 0; ct < 8; ++ct)
#pragma unroll
        for (int kh = 0; kh < 2; ++kh)
            acc[ct] = __builtin_amdgcn_mfma_f32_16x16x32_bf16(
                afr[kh], bfr[ct][kh], acc[ct], 0, 0, 0);

    float biasv[4];
#pragma unroll
    for (int i = 0; i < 4; ++i) biasv[i] = bias64[i * 16 + q];

    // h (ct 0..3) -> f16
#pragma unroll
    for (int ct = 0; ct < 4; ++ct)
#pragma unroll
        for (int j = 0; j < 4; ++j) {
            const int gr = rowBase + wave * 16 + rg * 4 + j;
            if (gr < n) h16[(size_t)gr * 64 + ct * 16 + q] = f2fh(acc[ct][j]);
        }
    // base (ct 4..7) + bias -> d_out
#pragma unroll
    for (int ct = 4; ct < 8; ++ct)
#pragma unroll
        for (int j = 0; j < 4; ++j) {
            const int gr = rowBase + wave * 16 + rg * 4 + j;
            if (gr < n)
                base[(size_t)gr * 64 + (ct - 4) * 16 + q] = acc[ct][j] + biasv[ct - 4];
        }
}

// ---------------- K2: counting sort by dst (conversion fused) ----------------
__global__ __launch_bounds__(BLK) void hist_kernel(
    const int* __restrict__ ei_raw, int* __restrict__ cnt, int n_edges) {
    __shared__ int s_is64;
    if (threadIdx.x == 0) {
        int all0 = 1;
        for (int i = 1; i < 128; i += 2) all0 &= (ei_raw[i] == 0);
        s_is64 = all0;
    }
    __syncthreads();
    const int gid = blockIdx.x * BLK + threadIdx.x;
    if (gid >= n_edges) return;
    const int d = s_is64 ? (int)((const long long*)ei_raw)[n_edges + gid]
                         : ei_raw[n_edges + gid];
    atomicAdd(&cnt[d], 1);
}

__global__ __launch_bounds__(BLK) void scan1(
    const int* __restrict__ cnt, int* __restrict__ offs,
    int* __restrict__ bsum, int n) {
    __shared__ int s[BLK];
    const int t = threadIdx.x;
    const int gid = blockIdx.x * BLK + t;
    const int v = (gid < n) ? cnt[gid] : 0;
    s[t] = v;
    __syncthreads();
#pragma unroll
    for (int o = 1; o < BLK; o <<= 1) {
        int u = (t >= o) ? s[t - o] : 0;
        __syncthreads();
        s[t] += u;
        __syncthreads();
    }
    if (gid < n) offs[gid] = s[t] - v;       // exclusive, block-local
    if (t == BLK - 1) bsum[blockIdx.x] = s[t];
}

// scan2+scan3 fused: each block re-scans the block sums (nb <= 256) in LDS.
__global__ __launch_bounds__(BLK) void scan23(
    int* __restrict__ offs, const int* __restrict__ bsum,
    int* __restrict__ cur, int n, int n_edges, int nb) {
    __shared__ int sb[BLK];
    const int t = threadIdx.x;
    const int v = (t < nb) ? bsum[t] : 0;
    sb[t] = v;
    __syncthreads();
#pragma unroll
    for (int o = 1; o < BLK; o <<= 1) {
        int u = (t >= o) ? sb[t - o] : 0;
        __syncthreads();
        sb[t] += u;
        __syncthreads();
    }
    sb[t] -= v;                               // exclusive
    __syncthreads();
    const int base = sb[blockIdx.x];
    const int gid = blockIdx.x * BLK + t;
    if (gid < n) {
        const int o = offs[gid] + base;
        offs[gid] = o;
        cur[gid] = o;
    }
    if (gid == 0) offs[n] = n_edges;
}

// Scatter: one 16B payload per edge at the sorted position:
// {src, w0|w1<<16, w2|w3<<16, 0} with w = f16(exp(leaky(e))).
__global__ __launch_bounds__(BLK) void scatter_kernel(
    const int* __restrict__ ei_raw, const float* __restrict__ a_src,
    const float* __restrict__ a_dst, int* __restrict__ cur,
    uint4* __restrict__ pay, int n_edges) {
    __shared__ int s_is64;
    if (threadIdx.x == 0) {
        int all0 = 1;
        for (int i = 1; i < 128; i += 2) all0 &= (ei_raw[i] == 0);
        s_is64 = all0;
    }
    __syncthreads();
    const int gid = blockIdx.x * BLK + threadIdx.x;
    if (gid >= n_edges) return;
    int s, d;
    if (s_is64) {
        const long long* e64 = (const long long*)ei_raw;
        s = (int)e64[gid];
        d = (int)e64[n_edges + gid];
    } else {
        s = ei_raw[gid];
        d = ei_raw[n_edges + gid];
    }
    const int pos = atomicAdd(&cur[d], 1);

    const float4 as = *reinterpret_cast<const float4*>(a_src + (size_t)s * 4);
    const float4 adv = *reinterpret_cast<const float4*>(a_dst + (size_t)d * 4);
    float e0 = as.x + adv.x, e1 = as.y + adv.y, e2 = as.z + adv.z, e3 = as.w + adv.w;
    e0 = e0 > 0.f ? e0 : 0.2f * e0;
    e1 = e1 > 0.f ? e1 : 0.2f * e1;
    e2 = e2 > 0.f ? e2 : 0.2f * e2;
    e3 = e3 > 0.f ? e3 : 0.2f * e3;
    uint4 p;
    p.x = (unsigned)s;
    p.y = (unsigned)f2fh(__expf(e0)) | ((unsigned)f2fh(__expf(e1)) << 16);
    p.z = (unsigned)f2fh(__expf(e2)) | ((unsigned)f2fh(__expf(e3)) << 16);
    p.w = 0;
    pay[pos] = p;
}

// ---------------- K3: gather aggregation + finalize --------------------------
// One wave per dst node; lane j owns feature j (head = j>>4). Per edge:
// one uniform 16B payload load + one f16 h-row gather. Sequential sum
// per feature (round-6 arithmetic order), no cross-lane ops in the loop.
__global__ __launch_bounds__(BLK) void aggregate_kernel(
    const uint4* __restrict__ pay, const int* __restrict__ offs,
    const unsigned short* __restrict__ h16,
    const float* __restrict__ a_src, const float* __restrict__ a_dst,
    float* __restrict__ out, int n_nodes) {
    const int wave = threadIdx.x >> 6, lane = threadIdx.x & 63;
    const int d = blockIdx.x * 4 + wave;
    if (d >= n_nodes) return;
    const int head = lane >> 4;
    const int beg = offs[d], end = offs[d + 1];

    // self-loop seed (exact f32 logits)
    float e = a_src[d * 4 + head] + a_dst[d * 4 + head];
    e = e > 0.f ? e : 0.2f * e;
    const float w = __expf(e);
    float acc = w * fh2f(h16[(size_t)d * 64 + lane]);
    float den = w;

#pragma unroll 4
    for (int j = beg; j < end; ++j) {
        const uint4 p = pay[j];                         // uniform address
        const unsigned pair = (head & 2) ? p.z : p.y;
        const unsigned short wu =
            (head & 1) ? (unsigned short)(pair >> 16) : (unsigned short)(pair & 0xffffu);
        const float ww = fh2f(wu);
        acc = fmaf(ww, fh2f(h16[(size_t)(int)p.x * 64 + lane]), acc);
        den += ww;
    }

    const float v = acc / den + out[(size_t)d * 64 + lane];
    out[(size_t)d * 64 + lane] = v > 0.f ? v : 0.1f * expm1f(v);
}

extern "C" void kernel_launch(void* const* d_in, const int* in_sizes, int n_in,
                              void* d_out, int out_size, void* d_ws, size_t ws_size,
                              hipStream_t stream) {
    const float* x         = (const float*)d_in[0];
    const int*   ei_raw    = (const int*)d_in[1];
    const float* W         = (const float*)d_in[2];
    const float* att_src   = (const float*)d_in[3];
    const float* att_dst   = (const float*)d_in[4];
    const float* conv_bias = (const float*)d_in[5];
    const float* skip_W    = (const float*)d_in[6];
    const float* skip_b    = (const float*)d_in[7];

    const int n_nodes = in_sizes[0] / 64;   // 50000
    const int n_edges = in_sizes[1] / 2;    // 800000

    char* wsb = (char*)d_ws;
    unsigned short* wfrag = (unsigned short*)wsb;                   // 16384 B
    uint4* pay    = (uint4*)(wsb + 16384);                          // E*16 B (16B-aligned)
    float* bias64 = (float*)(wsb + 16384 + (size_t)n_edges * 16);   // 64
    float* watt_s = bias64 + 64;                                    // 256
    float* watt_d = watt_s + 256;                                   // 256
    unsigned short* h16 = (unsigned short*)(watt_d + 256);          // N*64 u16
    float* a_src  = (float*)(h16 + (size_t)n_nodes * 64);           // N*4 (16B-aligned)
    float* a_dst  = a_src + (size_t)n_nodes * 4;                    // N*4
    int*   cnt    = (int*)(a_dst + (size_t)n_nodes * 4);            // N
    int*   offs   = cnt + n_nodes;                                  // N+1
    int*   cur    = offs + n_nodes + 1;                             // N
    int*   bsum   = cur + n_nodes;                                  // 256
    float* base   = (float*)d_out;

    const int nb_n = (n_nodes + BLK - 1) / BLK;           // 196
    const int nb_e = (n_edges + BLK - 1) / BLK;           // 3125

    prep_weights<<<nb_n + 1, BLK, 0, stream>>>(W, skip_W, conv_bias, skip_b,
                                               att_src, att_dst, wfrag, bias64,
                                               watt_s, watt_d, cnt, n_nodes);
    hist_kernel<<<nb_e, BLK, 0, stream>>>(ei_raw, cnt, n_edges);

    node_mfma<<<(n_nodes + 63) / 64, BLK, 0, stream>>>(
        x, wfrag, bias64, watt_s, watt_d, h16, base, a_src, a_dst, n_nodes);

    scan1<<<nb_n, BLK, 0, stream>>>(cnt, offs, bsum, n_nodes);
    scan23<<<nb_n, BLK, 0, stream>>>(offs, bsum, cur, n_nodes, n_edges, nb_n);
    scatter_kernel<<<nb_e, BLK, 0, stream>>>(ei_raw, a_src, a_dst, cur,
                                             pay, n_edges);

    aggregate_kernel<<<(n_nodes + 3) / 4, BLK, 0, stream>>>(
        pay, offs, h16, a_src, a_dst, (float*)d_out, n_nodes);
}

// Round 9
// 135.565 us; speedup vs baseline: 2.2875x; 1.1019x over previous
//
#include <hip/hip_runtime.h>
#include <hip/hip_bf16.h>
#include <math.h>

// GAT block: N=50000, E=800000, H_IN=64, HEADS=4, C=16 (F=64 out)
// Round 9: payload scatter eliminated (4B index-only sort; aggregate computes
// exp inline from L2-resident a_src). Aggregate: 16-lane groups, 4 nodes/wave
// (4x memory-level parallelism; per-node arithmetic order identical to r8).
// hist fused into node_mfma kernel (blockIdx split); cnt zeroed by memset.

#define BLK 256

typedef __attribute__((ext_vector_type(8))) short short8;
typedef __attribute__((ext_vector_type(4))) float f32x4;

static __device__ __forceinline__ unsigned short f2bf(float f) {
    union { float f; unsigned u; } v; v.f = f;
    return (unsigned short)((v.u + 0x7FFF + ((v.u >> 16) & 1)) >> 16);
}
static __device__ __forceinline__ unsigned short f2fh(float f) {
    union { _Float16 h; unsigned short u; } v; v.h = (_Float16)f; return v.u;
}
static __device__ __forceinline__ float fh2f(unsigned short u) {
    union { _Float16 h; unsigned short u; } v; v.u = u; return (float)v.h;
}

// ---------------- K0: pack weights + fold att vectors ------------------------
__global__ void prep_weights(const float* __restrict__ W,
                             const float* __restrict__ skipW,
                             const float* __restrict__ conv_bias,
                             const float* __restrict__ skip_b,
                             const float* __restrict__ att_src,
                             const float* __restrict__ att_dst,
                             unsigned short* __restrict__ wfrag,
                             float* __restrict__ bias64,
                             float* __restrict__ watt_s,
                             float* __restrict__ watt_d) {
    const int t = threadIdx.x;
    for (int idx = t; idx < 8192; idx += BLK) {
        const int j = idx & 7;
        const int lane = (idx >> 3) & 63;
        const int kh = (idx >> 9) & 1;
        const int ct = idx >> 10;
        const int k = kh * 32 + (lane >> 4) * 8 + j;
        const int c = ct * 16 + (lane & 15);
        const float v = (c < 64) ? W[k * 64 + c] : skipW[k * 64 + (c - 64)];
        wfrag[idx] = f2bf(v);
    }
    if (t < 64) bias64[t] = conv_bias[t] + skip_b[t];
    {   // t in [0,256): hh = t>>6, k = t&63
        const int hh = t >> 6, k = t & 63;
        float ssum = 0.f, dsum = 0.f;
#pragma unroll
        for (int c = 0; c < 16; ++c) {
            const float wv = W[k * 64 + hh * 16 + c];
            ssum = fmaf(wv, att_src[hh * 16 + c], ssum);
            dsum = fmaf(wv, att_dst[hh * 16 + c], dsum);
        }
        watt_s[hh * 64 + k] = ssum;
        watt_d[hh * 64 + k] = dsum;
    }
}

// ---------------- K1: fused node transform (MFMA) | histogram ----------------
// Blocks [0, nbNode): node transform (64 rows each).
// Blocks [nbNode, nbNode+nbE): edge-dst histogram (conversion fused).
__global__ __launch_bounds__(BLK) void node_hist(
    const float* __restrict__ x, const unsigned short* __restrict__ wfrag,
    const float* __restrict__ bias64, const float* __restrict__ watt_s,
    const float* __restrict__ watt_d,
    unsigned short* __restrict__ h16, float* __restrict__ base,
    float* __restrict__ a_src, float* __restrict__ a_dst, int n,
    const int* __restrict__ ei_raw, int* __restrict__ cnt, int n_edges,
    int nbNode) {
    __shared__ unsigned short sfrag[4 * 64 * 16];  // [wave][lane][kh*8+j], 8KB
    __shared__ float swatt[512];                   // watt_s | watt_d
    __shared__ int s_is64;
    const int t = threadIdx.x;

    if (blockIdx.x >= nbNode) {   // ---------------- histogram part
        if (t == 0) {
            int all0 = 1;
            for (int i = 1; i < 128; i += 2) all0 &= (ei_raw[i] == 0);
            s_is64 = all0;
        }
        __syncthreads();
        const int gid = (blockIdx.x - nbNode) * BLK + t;
        if (gid >= n_edges) return;
        const int d = s_is64 ? (int)((const long long*)ei_raw)[n_edges + gid]
                             : ei_raw[n_edges + gid];
        atomicAdd(&cnt[d], 1);
        return;
    }

    // ---------------- node transform part
    const int rowBase = blockIdx.x * 64;

    swatt[t] = watt_s[t];
    swatt[256 + t] = watt_d[t];

    const int r = t >> 2;
    const int c0 = (t & 3) << 4;
    const int grow = rowBase + r;
    float vals[16];
    if (grow < n) {
        const float4* xp = reinterpret_cast<const float4*>(x + (size_t)grow * 64 + c0);
        float4 a0 = xp[0], a1 = xp[1], a2 = xp[2], a3 = xp[3];
        vals[0]=a0.x; vals[1]=a0.y; vals[2]=a0.z; vals[3]=a0.w;
        vals[4]=a1.x; vals[5]=a1.y; vals[6]=a1.z; vals[7]=a1.w;
        vals[8]=a2.x; vals[9]=a2.y; vals[10]=a2.z; vals[11]=a2.w;
        vals[12]=a3.x; vals[13]=a3.y; vals[14]=a3.z; vals[15]=a3.w;
    } else {
#pragma unroll
        for (int i = 0; i < 16; ++i) vals[i] = 0.f;
    }

    // write the two bf16 k-octets straight into A-fragment slots
    {
        const int r15 = r & 15, wv = r >> 4;
#pragma unroll
        for (int oo = 0; oo < 2; ++oo) {
            const int oct = (t & 3) * 2 + oo;       // 0..7
            const int kh = oct >> 2, rg = oct & 3;
            const int lane = rg * 16 + r15;
            short8 p;
#pragma unroll
            for (int i = 0; i < 8; ++i) p[i] = (short)f2bf(vals[oo * 8 + i]);
            *reinterpret_cast<short8*>(&sfrag[((wv * 64 + lane) * 2 + kh) * 8]) = p;
        }
    }
    __syncthreads();

    // ---- f32 attention logits
    {
#pragma unroll
        for (int hh = 0; hh < 4; ++hh) {
            float s = 0.f, dd = 0.f;
#pragma unroll
            for (int i = 0; i < 16; ++i) {
                s  = fmaf(vals[i], swatt[hh * 64 + c0 + i], s);
                dd = fmaf(vals[i], swatt[256 + hh * 64 + c0 + i], dd);
            }
            s  += __shfl_xor(s, 1);  s  += __shfl_xor(s, 2);
            dd += __shfl_xor(dd, 1); dd += __shfl_xor(dd, 2);
            if ((t & 3) == 0 && grow < n) {
                a_src[grow * 4 + hh] = s;
                a_dst[grow * 4 + hh] = dd;
            }
        }
    }

    // ---- MFMA: 16 rows/wave x 128 cols
    const int wave = t >> 6, lane = t & 63;
    const int q = lane & 15, rg = lane >> 4;

    short8 bfr[8][2];
#pragma unroll
    for (int ct = 0; ct < 8; ++ct)
#pragma unroll
        for (int kh = 0; kh < 2; ++kh)
            bfr[ct][kh] = *reinterpret_cast<const short8*>(
                wfrag + (size_t)((ct * 2 + kh) * 64 + lane) * 8);

    short8 afr[2];
#pragma unroll
    for (int kh = 0; kh < 2; ++kh)
        afr[kh] = *reinterpret_cast<const short8*>(
            &sfrag[((wave * 64 + lane) * 2 + kh) * 8]);

    f32x4 acc[8];
#pragma unroll
    for (int i = 0; i < 8; ++i) { acc[i][0]=0.f; acc[i][1]=0.f; acc[i][2]=0.f; acc[i][3]=0.f; }
#pragma unroll
    for (int ct = 0; ct < 8; ++ct)
#pragma unroll
        for (int kh = 0; kh < 2; ++kh)
            acc[ct] = __builtin_amdgcn_mfma_f32_16x16x32_bf16(
                afr[kh], bfr[ct][kh], acc[ct], 0, 0, 0);

    float biasv[4];
#pragma unroll
    for (int i = 0; i < 4; ++i) biasv[i] = bias64[i * 16 + q];

    // h (ct 0..3) -> f16
#pragma unroll
    for (int ct = 0; ct < 4; ++ct)
#pragma unroll
        for (int j = 0; j < 4; ++j) {
            const int gr = rowBase + wave * 16 + rg * 4 + j;
            if (gr < n) h16[(size_t)gr * 64 + ct * 16 + q] = f2fh(acc[ct][j]);
        }
    // base (ct 4..7) + bias -> d_out
#pragma unroll
    for (int ct = 4; ct < 8; ++ct)
#pragma unroll
        for (int j = 0; j < 4; ++j) {
            const int gr = rowBase + wave * 16 + rg * 4 + j;
            if (gr < n)
                base[(size_t)gr * 64 + (ct - 4) * 16 + q] = acc[ct][j] + biasv[ct - 4];
        }
}

// ---------------- K2: scans --------------------------------------------------
__global__ __launch_bounds__(BLK) void scan1(
    const int* __restrict__ cnt, int* __restrict__ offs,
    int* __restrict__ bsum, int n) {
    __shared__ int s[BLK];
    const int t = threadIdx.x;
    const int gid = blockIdx.x * BLK + t;
    const int v = (gid < n) ? cnt[gid] : 0;
    s[t] = v;
    __syncthreads();
#pragma unroll
    for (int o = 1; o < BLK; o <<= 1) {
        int u = (t >= o) ? s[t - o] : 0;
        __syncthreads();
        s[t] += u;
        __syncthreads();
    }
    if (gid < n) offs[gid] = s[t] - v;       // exclusive, block-local
    if (t == BLK - 1) bsum[blockIdx.x] = s[t];
}

// scan2+scan3 fused: each block re-scans the block sums (nb <= 256) in LDS.
__global__ __launch_bounds__(BLK) void scan23(
    int* __restrict__ offs, const int* __restrict__ bsum,
    int* __restrict__ cur, int n, int n_edges, int nb) {
    __shared__ int sb[BLK];
    const int t = threadIdx.x;
    const int v = (t < nb) ? bsum[t] : 0;
    sb[t] = v;
    __syncthreads();
#pragma unroll
    for (int o = 1; o < BLK; o <<= 1) {
        int u = (t >= o) ? sb[t - o] : 0;
        __syncthreads();
        sb[t] += u;
        __syncthreads();
    }
    sb[t] -= v;                               // exclusive
    __syncthreads();
    const int base = sb[blockIdx.x];
    const int gid = blockIdx.x * BLK + t;
    if (gid < n) {
        const int o = offs[gid] + base;
        offs[gid] = o;
        cur[gid] = o;
    }
    if (gid == 0) offs[n] = n_edges;
}

// ---------------- K3: scatter (4B src index only) ----------------------------
__global__ __launch_bounds__(BLK) void scatter_kernel(
    const int* __restrict__ ei_raw, int* __restrict__ cur,
    int* __restrict__ sorted_src, int n_edges) {
    __shared__ int s_is64;
    if (threadIdx.x == 0) {
        int all0 = 1;
        for (int i = 1; i < 128; i += 2) all0 &= (ei_raw[i] == 0);
        s_is64 = all0;
    }
    __syncthreads();
    const int gid = blockIdx.x * BLK + threadIdx.x;
    if (gid >= n_edges) return;
    int s, d;
    if (s_is64) {
        const long long* e64 = (const long long*)ei_raw;
        s = (int)e64[gid];
        d = (int)e64[n_edges + gid];
    } else {
        s = ei_raw[gid];
        d = ei_raw[n_edges + gid];
    }
    const int pos = atomicAdd(&cur[d], 1);
    sorted_src[pos] = s;
}

// ---------------- K4: gather aggregation + finalize --------------------------
// 16-lane group per dst node (4 nodes/wave, 16 nodes/block). Lane q owns
// feature quad q*4..q*4+3 (head = q>>2). Per-node per-feature summation is
// strictly sequential over the sorted edge order (identical to round 8);
// w computed inline in exact f32 from L2-resident a_src/a_dst.
__global__ __launch_bounds__(BLK) void aggregate_kernel(
    const int* __restrict__ sorted_src, const int* __restrict__ offs,
    const unsigned short* __restrict__ h16,
    const float* __restrict__ a_src, const float* __restrict__ a_dst,
    float* __restrict__ out, int n_nodes) {
    const int g = threadIdx.x >> 4;          // group in block: 0..15
    const int q = threadIdx.x & 15;          // lane in group
    const int d = blockIdx.x * 16 + g;
    if (d >= n_nodes) return;
    const int head = q >> 2;
    const float ad = a_dst[d * 4 + head];
    const int beg = offs[d], end = offs[d + 1];

    // self-loop seed
    float e = a_src[d * 4 + head] + ad;
    e = e > 0.f ? e : 0.2f * e;
    const float w = __expf(e);
    float den = w;
    float acc0, acc1, acc2, acc3;
    {
        const ushort4 hp = *reinterpret_cast<const ushort4*>(
            h16 + (size_t)d * 64 + q * 4);
        acc0 = w * fh2f(hp.x); acc1 = w * fh2f(hp.y);
        acc2 = w * fh2f(hp.z); acc3 = w * fh2f(hp.w);
    }

#pragma unroll 4
    for (int j = beg; j < end; ++j) {
        const int s = sorted_src[j];
        float es = a_src[s * 4 + head] + ad;
        es = es > 0.f ? es : 0.2f * es;
        const float ww = __expf(es);
        const ushort4 hp = *reinterpret_cast<const ushort4*>(
            h16 + (size_t)s * 64 + q * 4);
        acc0 = fmaf(ww, fh2f(hp.x), acc0);
        acc1 = fmaf(ww, fh2f(hp.y), acc1);
        acc2 = fmaf(ww, fh2f(hp.z), acc2);
        acc3 = fmaf(ww, fh2f(hp.w), acc3);
        den += ww;
    }

    float* op = out + (size_t)d * 64 + q * 4;
    const float4 b = *reinterpret_cast<const float4*>(op);
    const float inv = 1.f / den;
    float r0 = fmaf(acc0, inv, b.x);
    float r1 = fmaf(acc1, inv, b.y);
    float r2 = fmaf(acc2, inv, b.z);
    float r3 = fmaf(acc3, inv, b.w);
    float4 r;
    r.x = r0 > 0.f ? r0 : 0.1f * expm1f(r0);
    r.y = r1 > 0.f ? r1 : 0.1f * expm1f(r1);
    r.z = r2 > 0.f ? r2 : 0.1f * expm1f(r2);
    r.w = r3 > 0.f ? r3 : 0.1f * expm1f(r3);
    *reinterpret_cast<float4*>(op) = r;
}

extern "C" void kernel_launch(void* const* d_in, const int* in_sizes, int n_in,
                              void* d_out, int out_size, void* d_ws, size_t ws_size,
                              hipStream_t stream) {
    const float* x         = (const float*)d_in[0];
    const int*   ei_raw    = (const int*)d_in[1];
    const float* W         = (const float*)d_in[2];
    const float* att_src   = (const float*)d_in[3];
    const float* att_dst   = (const float*)d_in[4];
    const float* conv_bias = (const float*)d_in[5];
    const float* skip_W    = (const float*)d_in[6];
    const float* skip_b    = (const float*)d_in[7];

    const int n_nodes = in_sizes[0] / 64;   // 50000
    const int n_edges = in_sizes[1] / 2;    // 800000

    float* ws = (float*)d_ws;
    unsigned short* wfrag = (unsigned short*)ws;          // 8192 u16 (offset 0)
    float* bias64 = ws + 4096;                            // 64
    float* watt_s = bias64 + 64;                          // 256
    float* watt_d = watt_s + 256;                         // 256
    unsigned short* h16 = (unsigned short*)(watt_d + 256);// N*64 u16
    float* a_src  = (float*)(h16 + (size_t)n_nodes * 64); // N*4 (16B-aligned)
    float* a_dst  = a_src + (size_t)n_nodes * 4;          // N*4
    int*   cnt    = (int*)(a_dst + (size_t)n_nodes * 4);  // N
    int*   offs   = cnt + n_nodes;                        // N+1
    int*   cur    = offs + n_nodes + 1;                   // N
    int*   bsum   = cur + n_nodes;                        // 256
    int*   sorted_src = bsum + 256;                       // E
    float* base   = (float*)d_out;

    const int nb_n = (n_nodes + BLK - 1) / BLK;           // 196
    const int nb_e = (n_edges + BLK - 1) / BLK;           // 3125
    const int nbNode = (n_nodes + 63) / 64;               // 782

    hipMemsetAsync(cnt, 0, (size_t)n_nodes * sizeof(int), stream);
    prep_weights<<<1, BLK, 0, stream>>>(W, skip_W, conv_bias, skip_b,
                                        att_src, att_dst, wfrag, bias64,
                                        watt_s, watt_d);

    node_hist<<<nbNode + nb_e, BLK, 0, stream>>>(
        x, wfrag, bias64, watt_s, watt_d, h16, base, a_src, a_dst, n_nodes,
        ei_raw, cnt, n_edges, nbNode);

    scan1<<<nb_n, BLK, 0, stream>>>(cnt, offs, bsum, n_nodes);
    scan23<<<nb_n, BLK, 0, stream>>>(offs, bsum, cur, n_nodes, n_edges, nb_n);
    scatter_kernel<<<nb_e, BLK, 0, stream>>>(ei_raw, cur, sorted_src, n_edges);

    aggregate_kernel<<<(n_nodes + 15) / 16, BLK, 0, stream>>>(
        sorted_src, offs, h16, a_src, a_dst, (float*)d_out, n_nodes);
}

// Round 10
// 106.159 us; speedup vs baseline: 2.9211x; 1.2770x over previous
//
#include <hip/hip_runtime.h>
#include <hip/hip_bf16.h>
#include <math.h>

// GAT block: N=50000, E=800000, H_IN=64, HEADS=4, C=16 (F=64 out)
// Round 10: write-thrash fix for the sort. Pass 1 (fused in node kernel):
// bucket edges by dst>>9 into dense per-bucket runs in tmp (8B uint2, runs
// line-merged), hist fused. Pass 2: one block per bucket, LDS counters,
// exclusive 33KB output region -> L2 write-merge. No `cur` array.
// Aggregate / node MFMA / scans unchanged from round 9.

#define BLK 256
#define NPB 512            // nodes per bucket
#define NBUCKET 128        // allocated (98 used)
#define BCAP 16384         // tmp capacity per bucket (mean 8192, +91 sigma)
#define EPB 2048           // edges per pass-1 block

typedef __attribute__((ext_vector_type(8))) short short8;
typedef __attribute__((ext_vector_type(4))) float f32x4;

static __device__ __forceinline__ unsigned short f2bf(float f) {
    union { float f; unsigned u; } v; v.f = f;
    return (unsigned short)((v.u + 0x7FFF + ((v.u >> 16) & 1)) >> 16);
}
static __device__ __forceinline__ unsigned short f2fh(float f) {
    union { _Float16 h; unsigned short u; } v; v.h = (_Float16)f; return v.u;
}
static __device__ __forceinline__ float fh2f(unsigned short u) {
    union { _Float16 h; unsigned short u; } v; v.u = u; return (float)v.h;
}

// ---------------- K0: pack weights + fold att vectors ------------------------
__global__ void prep_weights(const float* __restrict__ W,
                             const float* __restrict__ skipW,
                             const float* __restrict__ conv_bias,
                             const float* __restrict__ skip_b,
                             const float* __restrict__ att_src,
                             const float* __restrict__ att_dst,
                             unsigned short* __restrict__ wfrag,
                             float* __restrict__ bias64,
                             float* __restrict__ watt_s,
                             float* __restrict__ watt_d) {
    const int t = threadIdx.x;
    for (int idx = t; idx < 8192; idx += BLK) {
        const int j = idx & 7;
        const int lane = (idx >> 3) & 63;
        const int kh = (idx >> 9) & 1;
        const int ct = idx >> 10;
        const int k = kh * 32 + (lane >> 4) * 8 + j;
        const int c = ct * 16 + (lane & 15);
        const float v = (c < 64) ? W[k * 64 + c] : skipW[k * 64 + (c - 64)];
        wfrag[idx] = f2bf(v);
    }
    if (t < 64) bias64[t] = conv_bias[t] + skip_b[t];
    {   // t in [0,256): hh = t>>6, k = t&63
        const int hh = t >> 6, k = t & 63;
        float ssum = 0.f, dsum = 0.f;
#pragma unroll
        for (int c = 0; c < 16; ++c) {
            const float wv = W[k * 64 + hh * 16 + c];
            ssum = fmaf(wv, att_src[hh * 16 + c], ssum);
            dsum = fmaf(wv, att_dst[hh * 16 + c], dsum);
        }
        watt_s[hh * 64 + k] = ssum;
        watt_d[hh * 64 + k] = dsum;
    }
}

// ---------------- K1: fused node transform (MFMA) | edge bucketing -----------
// Blocks [0, nbNode): node transform (64 rows each).
// Blocks [nbNode, nbNode+nbB): bucket pass over EPB edges each:
//   per edge: hist atomicAdd(cnt[d]) + LDS bucket rank; per (block,bucket)
//   one global reservation; dense uint2 {s,d} runs into tmp[b*BCAP+..].
__global__ __launch_bounds__(BLK) void node_bucket(
    const float* __restrict__ x, const unsigned short* __restrict__ wfrag,
    const float* __restrict__ bias64, const float* __restrict__ watt_s,
    const float* __restrict__ watt_d,
    unsigned short* __restrict__ h16, float* __restrict__ base,
    float* __restrict__ a_src, float* __restrict__ a_dst, int n,
    const int* __restrict__ ei_raw, int* __restrict__ cnt,
    int* __restrict__ bcur, uint2* __restrict__ tmp, int n_edges,
    int nbNode) {
    __shared__ unsigned short sfrag[4 * 64 * 16];  // 8KB (node part)
    __shared__ float swatt[512];                   // 2KB (node part)
    __shared__ int s_is64;
    __shared__ int bh[NBUCKET];                    // bucket part
    __shared__ int gb[NBUCKET];
    const int t = threadIdx.x;

    if (blockIdx.x >= nbNode) {   // ---------------- bucket part
        if (t == 0) {
            int all0 = 1;
            for (int i = 1; i < 128; i += 2) all0 &= (ei_raw[i] == 0);
            s_is64 = all0;
        }
        if (t < NBUCKET) bh[t] = 0;
        __syncthreads();
        const int e0 = (blockIdx.x - nbNode) * EPB;
        const int is64 = s_is64;
        const long long* e64 = (const long long*)ei_raw;
        int sarr[8], darr[8], rarr[8];
#pragma unroll
        for (int i = 0; i < 8; ++i) {
            const int e = e0 + i * BLK + t;
            if (e < n_edges) {
                if (is64) {
                    sarr[i] = (int)e64[e];
                    darr[i] = (int)e64[n_edges + e];
                } else {
                    sarr[i] = ei_raw[e];
                    darr[i] = ei_raw[n_edges + e];
                }
            } else darr[i] = -1;
        }
#pragma unroll
        for (int i = 0; i < 8; ++i) {
            if (darr[i] >= 0) {
                atomicAdd(&cnt[darr[i]], 1);
                rarr[i] = atomicAdd(&bh[darr[i] >> 9], 1);
            }
        }
        __syncthreads();
        if (t < NBUCKET && bh[t] > 0) gb[t] = atomicAdd(&bcur[t], bh[t]);
        __syncthreads();
#pragma unroll
        for (int i = 0; i < 8; ++i) {
            if (darr[i] >= 0) {
                const int b = darr[i] >> 9;
                const int r = gb[b] + rarr[i];
                if (r < BCAP)
                    tmp[(size_t)b * BCAP + r] = make_uint2((unsigned)sarr[i],
                                                           (unsigned)darr[i]);
            }
        }
        return;
    }

    // ---------------- node transform part (unchanged from round 9)
    const int rowBase = blockIdx.x * 64;

    swatt[t] = watt_s[t];
    swatt[256 + t] = watt_d[t];

    const int r = t >> 2;
    const int c0 = (t & 3) << 4;
    const int grow = rowBase + r;
    float vals[16];
    if (grow < n) {
        const float4* xp = reinterpret_cast<const float4*>(x + (size_t)grow * 64 + c0);
        float4 a0 = xp[0], a1 = xp[1], a2 = xp[2], a3 = xp[3];
        vals[0]=a0.x; vals[1]=a0.y; vals[2]=a0.z; vals[3]=a0.w;
        vals[4]=a1.x; vals[5]=a1.y; vals[6]=a1.z; vals[7]=a1.w;
        vals[8]=a2.x; vals[9]=a2.y; vals[10]=a2.z; vals[11]=a2.w;
        vals[12]=a3.x; vals[13]=a3.y; vals[14]=a3.z; vals[15]=a3.w;
    } else {
#pragma unroll
        for (int i = 0; i < 16; ++i) vals[i] = 0.f;
    }

    {
        const int r15 = r & 15, wv = r >> 4;
#pragma unroll
        for (int oo = 0; oo < 2; ++oo) {
            const int oct = (t & 3) * 2 + oo;       // 0..7
            const int kh = oct >> 2, rg = oct & 3;
            const int lane = rg * 16 + r15;
            short8 p;
#pragma unroll
            for (int i = 0; i < 8; ++i) p[i] = (short)f2bf(vals[oo * 8 + i]);
            *reinterpret_cast<short8*>(&sfrag[((wv * 64 + lane) * 2 + kh) * 8]) = p;
        }
    }
    __syncthreads();

    {
#pragma unroll
        for (int hh = 0; hh < 4; ++hh) {
            float s = 0.f, dd = 0.f;
#pragma unroll
            for (int i = 0; i < 16; ++i) {
                s  = fmaf(vals[i], swatt[hh * 64 + c0 + i], s);
                dd = fmaf(vals[i], swatt[256 + hh * 64 + c0 + i], dd);
            }
            s  += __shfl_xor(s, 1);  s  += __shfl_xor(s, 2);
            dd += __shfl_xor(dd, 1); dd += __shfl_xor(dd, 2);
            if ((t & 3) == 0 && grow < n) {
                a_src[grow * 4 + hh] = s;
                a_dst[grow * 4 + hh] = dd;
            }
        }
    }

    const int wave = t >> 6, lane = t & 63;
    const int q = lane & 15, rg = lane >> 4;

    short8 bfr[8][2];
#pragma unroll
    for (int ct = 0; ct < 8; ++ct)
#pragma unroll
        for (int kh = 0; kh < 2; ++kh)
            bfr[ct][kh] = *reinterpret_cast<const short8*>(
                wfrag + (size_t)((ct * 2 + kh) * 64 + lane) * 8);

    short8 afr[2];
#pragma unroll
    for (int kh = 0; kh < 2; ++kh)
        afr[kh] = *reinterpret_cast<const short8*>(
            &sfrag[((wave * 64 + lane) * 2 + kh) * 8]);

    f32x4 acc[8];
#pragma unroll
    for (int i = 0; i < 8; ++i) { acc[i][0]=0.f; acc[i][1]=0.f; acc[i][2]=0.f; acc[i][3]=0.f; }
#pragma unroll
    for (int ct = 0; ct < 8; ++ct)
#pragma unroll
        for (int kh = 0; kh < 2; ++kh)
            acc[ct] = __builtin_amdgcn_mfma_f32_16x16x32_bf16(
                afr[kh], bfr[ct][kh], acc[ct], 0, 0, 0);

    float biasv[4];
#pragma unroll
    for (int i = 0; i < 4; ++i) biasv[i] = bias64[i * 16 + q];

#pragma unroll
    for (int ct = 0; ct < 4; ++ct)
#pragma unroll
        for (int j = 0; j < 4; ++j) {
            const int gr = rowBase + wave * 16 + rg * 4 + j;
            if (gr < n) h16[(size_t)gr * 64 + ct * 16 + q] = f2fh(acc[ct][j]);
        }
#pragma unroll
    for (int ct = 4; ct < 8; ++ct)
#pragma unroll
        for (int j = 0; j < 4; ++j) {
            const int gr = rowBase + wave * 16 + rg * 4 + j;
            if (gr < n)
                base[(size_t)gr * 64 + (ct - 4) * 16 + q] = acc[ct][j] + biasv[ct - 4];
        }
}

// ---------------- K2: scans --------------------------------------------------
__global__ __launch_bounds__(BLK) void scan1(
    const int* __restrict__ cnt, int* __restrict__ offs,
    int* __restrict__ bsum, int n) {
    __shared__ int s[BLK];
    const int t = threadIdx.x;
    const int gid = blockIdx.x * BLK + t;
    const int v = (gid < n) ? cnt[gid] : 0;
    s[t] = v;
    __syncthreads();
#pragma unroll
    for (int o = 1; o < BLK; o <<= 1) {
        int u = (t >= o) ? s[t - o] : 0;
        __syncthreads();
        s[t] += u;
        __syncthreads();
    }
    if (gid < n) offs[gid] = s[t] - v;       // exclusive, block-local
    if (t == BLK - 1) bsum[blockIdx.x] = s[t];
}

// scan2+scan3 fused: each block re-scans the block sums (nb <= 256) in LDS.
__global__ __launch_bounds__(BLK) void scan23(
    int* __restrict__ offs, const int* __restrict__ bsum,
    int n, int n_edges, int nb) {
    __shared__ int sb[BLK];
    const int t = threadIdx.x;
    const int v = (t < nb) ? bsum[t] : 0;
    sb[t] = v;
    __syncthreads();
#pragma unroll
    for (int o = 1; o < BLK; o <<= 1) {
        int u = (t >= o) ? sb[t - o] : 0;
        __syncthreads();
        sb[t] += u;
        __syncthreads();
    }
    sb[t] -= v;                               // exclusive
    __syncthreads();
    const int base = sb[blockIdx.x];
    const int gid = blockIdx.x * BLK + t;
    if (gid < n) offs[gid] += base;
    if (gid == 0) offs[n] = n_edges;
}

// ---------------- K3: bucket-local scatter (pass 2) --------------------------
// One block per bucket; exclusive ownership of the final output region.
// Positions via LDS counters (no global atomics); writes L2-merge.
__global__ __launch_bounds__(BLK) void scatter2(
    const uint2* __restrict__ tmp, const int* __restrict__ offs,
    int* __restrict__ sorted_src, int n_nodes) {
    __shared__ int loffs[NPB];
    __shared__ int lcur[NPB];
    const int b = blockIdx.x;
    const int dbase = b << 9;
    const int ncount = min(NPB, n_nodes - dbase);
    const int t = threadIdx.x;
    for (int k = t; k < ncount; k += BLK) {
        loffs[k] = offs[dbase + k];
        lcur[k] = 0;
    }
    __syncthreads();
    const int cntb = offs[dbase + ncount] - offs[dbase];
    const uint2* tb = tmp + (size_t)b * BCAP;
    for (int i = t; i < cntb; i += BLK) {
        const uint2 p = tb[i];
        const int dl = (int)p.y - dbase;
        const int pos = loffs[dl] + atomicAdd(&lcur[dl], 1);
        sorted_src[pos] = (int)p.x;
    }
}

// ---------------- K4: gather aggregation + finalize (round-9 verbatim) -------
__global__ __launch_bounds__(BLK) void aggregate_kernel(
    const int* __restrict__ sorted_src, const int* __restrict__ offs,
    const unsigned short* __restrict__ h16,
    const float* __restrict__ a_src, const float* __restrict__ a_dst,
    float* __restrict__ out, int n_nodes) {
    const int g = threadIdx.x >> 4;          // group in block: 0..15
    const int q = threadIdx.x & 15;          // lane in group
    const int d = blockIdx.x * 16 + g;
    if (d >= n_nodes) return;
    const int head = q >> 2;
    const float ad = a_dst[d * 4 + head];
    const int beg = offs[d], end = offs[d + 1];

    // self-loop seed
    float e = a_src[d * 4 + head] + ad;
    e = e > 0.f ? e : 0.2f * e;
    const float w = __expf(e);
    float den = w;
    float acc0, acc1, acc2, acc3;
    {
        const ushort4 hp = *reinterpret_cast<const ushort4*>(
            h16 + (size_t)d * 64 + q * 4);
        acc0 = w * fh2f(hp.x); acc1 = w * fh2f(hp.y);
        acc2 = w * fh2f(hp.z); acc3 = w * fh2f(hp.w);
    }

#pragma unroll 4
    for (int j = beg; j < end; ++j) {
        const int s = sorted_src[j];
        float es = a_src[s * 4 + head] + ad;
        es = es > 0.f ? es : 0.2f * es;
        const float ww = __expf(es);
        const ushort4 hp = *reinterpret_cast<const ushort4*>(
            h16 + (size_t)s * 64 + q * 4);
        acc0 = fmaf(ww, fh2f(hp.x), acc0);
        acc1 = fmaf(ww, fh2f(hp.y), acc1);
        acc2 = fmaf(ww, fh2f(hp.z), acc2);
        acc3 = fmaf(ww, fh2f(hp.w), acc3);
        den += ww;
    }

    float* op = out + (size_t)d * 64 + q * 4;
    const float4 b = *reinterpret_cast<const float4*>(op);
    const float inv = 1.f / den;
    float r0 = fmaf(acc0, inv, b.x);
    float r1 = fmaf(acc1, inv, b.y);
    float r2 = fmaf(acc2, inv, b.z);
    float r3 = fmaf(acc3, inv, b.w);
    float4 r;
    r.x = r0 > 0.f ? r0 : 0.1f * expm1f(r0);
    r.y = r1 > 0.f ? r1 : 0.1f * expm1f(r1);
    r.z = r2 > 0.f ? r2 : 0.1f * expm1f(r2);
    r.w = r3 > 0.f ? r3 : 0.1f * expm1f(r3);
    *reinterpret_cast<float4*>(op) = r;
}

extern "C" void kernel_launch(void* const* d_in, const int* in_sizes, int n_in,
                              void* d_out, int out_size, void* d_ws, size_t ws_size,
                              hipStream_t stream) {
    const float* x         = (const float*)d_in[0];
    const int*   ei_raw    = (const int*)d_in[1];
    const float* W         = (const float*)d_in[2];
    const float* att_src   = (const float*)d_in[3];
    const float* att_dst   = (const float*)d_in[4];
    const float* conv_bias = (const float*)d_in[5];
    const float* skip_W    = (const float*)d_in[6];
    const float* skip_b    = (const float*)d_in[7];

    const int n_nodes = in_sizes[0] / 64;   // 50000
    const int n_edges = in_sizes[1] / 2;    // 800000

    float* ws = (float*)d_ws;
    unsigned short* wfrag = (unsigned short*)ws;            // 4096 f-slots
    float* bias64 = ws + 4096;                              // 64
    float* watt_s = bias64 + 64;                            // 256
    float* watt_d = watt_s + 256;                           // 256
    uint2* tmp    = (uint2*)(watt_d + 256);                 // NBUCKET*BCAP*2 f-slots (8B-aligned)
    float* after_tmp = (float*)(tmp + (size_t)NBUCKET * BCAP);
    unsigned short* h16 = (unsigned short*)after_tmp;       // N*64 u16
    float* a_src  = (float*)(h16 + (size_t)n_nodes * 64);   // N*4
    float* a_dst  = a_src + (size_t)n_nodes * 4;            // N*4
    int*   cnt    = (int*)(a_dst + (size_t)n_nodes * 4);    // N
    int*   bcur   = cnt + n_nodes;                          // NBUCKET (memset with cnt)
    int*   offs   = bcur + NBUCKET;                         // N+1
    int*   bsum   = offs + n_nodes + 1;                     // 256
    int*   sorted_src = bsum + 256;                         // E
    float* base   = (float*)d_out;

    const int nb_n = (n_nodes + BLK - 1) / BLK;             // 196
    const int nbNode = (n_nodes + 63) / 64;                 // 782
    const int nbB = (n_edges + EPB - 1) / EPB;              // 391
    const int nbBucket = (n_nodes + NPB - 1) / NPB;         // 98

    hipMemsetAsync(cnt, 0, (size_t)(n_nodes + NBUCKET) * sizeof(int), stream);
    prep_weights<<<1, BLK, 0, stream>>>(W, skip_W, conv_bias, skip_b,
                                        att_src, att_dst, wfrag, bias64,
                                        watt_s, watt_d);

    node_bucket<<<nbNode + nbB, BLK, 0, stream>>>(
        x, wfrag, bias64, watt_s, watt_d, h16, base, a_src, a_dst, n_nodes,
        ei_raw, cnt, bcur, tmp, n_edges, nbNode);

    scan1<<<nb_n, BLK, 0, stream>>>(cnt, offs, bsum, n_nodes);
    scan23<<<nb_n, BLK, 0, stream>>>(offs, bsum, n_nodes, n_edges, nb_n);
    scatter2<<<nbBucket, BLK, 0, stream>>>(tmp, offs, sorted_src, n_nodes);

    aggregate_kernel<<<(n_nodes + 15) / 16, BLK, 0, stream>>>(
        sorted_src, offs, h16, a_src, a_dst, (float*)d_out, n_nodes);
}

// Round 11
// 80.460 us; speedup vs baseline: 3.8541x; 1.3194x over previous
//
#include <hip/hip_runtime.h>
#include <hip/hip_bf16.h>
#include <math.h>

// GAT block: N=50000, E=800000, H_IN=64, HEADS=4, C=16 (F=64 out)
// Round 11: atomic-free sort. The 800k device-scope atomicAdds cost ~52MB
// of HBM line writebacks (~50us). Replaced by: LDS per-block bucket counts
// -> plain blockcnt stores -> scan of 38318-entry matrix -> exact-position
// dense bucket writes -> per-bucket LDS hist/scan producing offs + sorted_src.
// Node MFMA + aggregate byte-identical to round 10.

#define BLK 256
#define NPB 512            // nodes per bucket
#define NBUCKET 128        // allocated LDS counters (98 used)
#define EPB 2048           // edges per bucketing block

typedef __attribute__((ext_vector_type(8))) short short8;
typedef __attribute__((ext_vector_type(4))) float f32x4;

static __device__ __forceinline__ unsigned short f2bf(float f) {
    union { float f; unsigned u; } v; v.f = f;
    return (unsigned short)((v.u + 0x7FFF + ((v.u >> 16) & 1)) >> 16);
}
static __device__ __forceinline__ unsigned short f2fh(float f) {
    union { _Float16 h; unsigned short u; } v; v.h = (_Float16)f; return v.u;
}
static __device__ __forceinline__ float fh2f(unsigned short u) {
    union { _Float16 h; unsigned short u; } v; v.u = u; return (float)v.h;
}

// ---------------- K0: pack weights + fold att vectors ------------------------
__global__ void prep_weights(const float* __restrict__ W,
                             const float* __restrict__ skipW,
                             const float* __restrict__ conv_bias,
                             const float* __restrict__ skip_b,
                             const float* __restrict__ att_src,
                             const float* __restrict__ att_dst,
                             unsigned short* __restrict__ wfrag,
                             float* __restrict__ bias64,
                             float* __restrict__ watt_s,
                             float* __restrict__ watt_d) {
    const int t = threadIdx.x;
    for (int idx = t; idx < 8192; idx += BLK) {
        const int j = idx & 7;
        const int lane = (idx >> 3) & 63;
        const int kh = (idx >> 9) & 1;
        const int ct = idx >> 10;
        const int k = kh * 32 + (lane >> 4) * 8 + j;
        const int c = ct * 16 + (lane & 15);
        const float v = (c < 64) ? W[k * 64 + c] : skipW[k * 64 + (c - 64)];
        wfrag[idx] = f2bf(v);
    }
    if (t < 64) bias64[t] = conv_bias[t] + skip_b[t];
    {   // t in [0,256): hh = t>>6, k = t&63
        const int hh = t >> 6, k = t & 63;
        float ssum = 0.f, dsum = 0.f;
#pragma unroll
        for (int c = 0; c < 16; ++c) {
            const float wv = W[k * 64 + hh * 16 + c];
            ssum = fmaf(wv, att_src[hh * 16 + c], ssum);
            dsum = fmaf(wv, att_dst[hh * 16 + c], dsum);
        }
        watt_s[hh * 64 + k] = ssum;
        watt_d[hh * 64 + k] = dsum;
    }
}

// ---------------- K1: fused node transform (MFMA) | bucket COUNT -------------
// Blocks [0, nbNode): node transform. Blocks [nbNode, nbNode+nbB): per-block
// LDS bucket histogram of EPB dst values -> plain stores to blockcnt.
__global__ __launch_bounds__(BLK) void node_bcount(
    const float* __restrict__ x, const unsigned short* __restrict__ wfrag,
    const float* __restrict__ bias64, const float* __restrict__ watt_s,
    const float* __restrict__ watt_d,
    unsigned short* __restrict__ h16, float* __restrict__ base,
    float* __restrict__ a_src, float* __restrict__ a_dst, int n,
    const int* __restrict__ ei_raw, int* __restrict__ blockcnt,
    int n_edges, int nbNode, int nbB, int nbBucket) {
    __shared__ unsigned short sfrag[4 * 64 * 16];  // 8KB (node part)
    __shared__ float swatt[512];                   // 2KB (node part)
    __shared__ int s_is64;
    __shared__ int bh[NBUCKET];
    const int t = threadIdx.x;

    if (blockIdx.x >= nbNode) {   // ---------------- count part (dst only)
        if (t == 0) {
            int all0 = 1;
            for (int i = 1; i < 128; i += 2) all0 &= (ei_raw[i] == 0);
            s_is64 = all0;
        }
        if (t < NBUCKET) bh[t] = 0;
        __syncthreads();
        const int blk = blockIdx.x - nbNode;
        const int e0 = blk * EPB;
        const int is64 = s_is64;
        const long long* e64 = (const long long*)ei_raw;
#pragma unroll
        for (int i = 0; i < 8; ++i) {
            const int e = e0 + i * BLK + t;
            if (e < n_edges) {
                const int d = is64 ? (int)e64[n_edges + e] : ei_raw[n_edges + e];
                atomicAdd(&bh[d >> 9], 1);          // LDS atomic only
            }
        }
        __syncthreads();
        for (int b = t; b < nbBucket; b += BLK)
            blockcnt[(size_t)b * nbB + blk] = bh[b];
        return;
    }

    // ---------------- node transform part (unchanged)
    const int rowBase = blockIdx.x * 64;

    swatt[t] = watt_s[t];
    swatt[256 + t] = watt_d[t];

    const int r = t >> 2;
    const int c0 = (t & 3) << 4;
    const int grow = rowBase + r;
    float vals[16];
    if (grow < n) {
        const float4* xp = reinterpret_cast<const float4*>(x + (size_t)grow * 64 + c0);
        float4 a0 = xp[0], a1 = xp[1], a2 = xp[2], a3 = xp[3];
        vals[0]=a0.x; vals[1]=a0.y; vals[2]=a0.z; vals[3]=a0.w;
        vals[4]=a1.x; vals[5]=a1.y; vals[6]=a1.z; vals[7]=a1.w;
        vals[8]=a2.x; vals[9]=a2.y; vals[10]=a2.z; vals[11]=a2.w;
        vals[12]=a3.x; vals[13]=a3.y; vals[14]=a3.z; vals[15]=a3.w;
    } else {
#pragma unroll
        for (int i = 0; i < 16; ++i) vals[i] = 0.f;
    }

    {
        const int r15 = r & 15, wv = r >> 4;
#pragma unroll
        for (int oo = 0; oo < 2; ++oo) {
            const int oct = (t & 3) * 2 + oo;       // 0..7
            const int kh = oct >> 2, rg = oct & 3;
            const int lane = rg * 16 + r15;
            short8 p;
#pragma unroll
            for (int i = 0; i < 8; ++i) p[i] = (short)f2bf(vals[oo * 8 + i]);
            *reinterpret_cast<short8*>(&sfrag[((wv * 64 + lane) * 2 + kh) * 8]) = p;
        }
    }
    __syncthreads();

    {
#pragma unroll
        for (int hh = 0; hh < 4; ++hh) {
            float s = 0.f, dd = 0.f;
#pragma unroll
            for (int i = 0; i < 16; ++i) {
                s  = fmaf(vals[i], swatt[hh * 64 + c0 + i], s);
                dd = fmaf(vals[i], swatt[256 + hh * 64 + c0 + i], dd);
            }
            s  += __shfl_xor(s, 1);  s  += __shfl_xor(s, 2);
            dd += __shfl_xor(dd, 1); dd += __shfl_xor(dd, 2);
            if ((t & 3) == 0 && grow < n) {
                a_src[grow * 4 + hh] = s;
                a_dst[grow * 4 + hh] = dd;
            }
        }
    }

    const int wave = t >> 6, lane = t & 63;
    const int q = lane & 15, rg = lane >> 4;

    short8 bfr[8][2];
#pragma unroll
    for (int ct = 0; ct < 8; ++ct)
#pragma unroll
        for (int kh = 0; kh < 2; ++kh)
            bfr[ct][kh] = *reinterpret_cast<const short8*>(
                wfrag + (size_t)((ct * 2 + kh) * 64 + lane) * 8);

    short8 afr[2];
#pragma unroll
    for (int kh = 0; kh < 2; ++kh)
        afr[kh] = *reinterpret_cast<const short8*>(
            &sfrag[((wave * 64 + lane) * 2 + kh) * 8]);

    f32x4 acc[8];
#pragma unroll
    for (int i = 0; i < 8; ++i) { acc[i][0]=0.f; acc[i][1]=0.f; acc[i][2]=0.f; acc[i][3]=0.f; }
#pragma unroll
    for (int ct = 0; ct < 8; ++ct)
#pragma unroll
        for (int kh = 0; kh < 2; ++kh)
            acc[ct] = __builtin_amdgcn_mfma_f32_16x16x32_bf16(
                afr[kh], bfr[ct][kh], acc[ct], 0, 0, 0);

    float biasv[4];
#pragma unroll
    for (int i = 0; i < 4; ++i) biasv[i] = bias64[i * 16 + q];

#pragma unroll
    for (int ct = 0; ct < 4; ++ct)
#pragma unroll
        for (int j = 0; j < 4; ++j) {
            const int gr = rowBase + wave * 16 + rg * 4 + j;
            if (gr < n) h16[(size_t)gr * 64 + ct * 16 + q] = f2fh(acc[ct][j]);
        }
#pragma unroll
    for (int ct = 4; ct < 8; ++ct)
#pragma unroll
        for (int j = 0; j < 4; ++j) {
            const int gr = rowBase + wave * 16 + rg * 4 + j;
            if (gr < n)
                base[(size_t)gr * 64 + (ct - 4) * 16 + q] = acc[ct][j] + biasv[ct - 4];
        }
}

// ---------------- K2/K3: scans over blockcnt (bucket-major) ------------------
__global__ __launch_bounds__(BLK) void scan1(
    const int* __restrict__ cnt, int* __restrict__ offs,
    int* __restrict__ bsum, int n) {
    __shared__ int s[BLK];
    const int t = threadIdx.x;
    const int gid = blockIdx.x * BLK + t;
    const int v = (gid < n) ? cnt[gid] : 0;
    s[t] = v;
    __syncthreads();
#pragma unroll
    for (int o = 1; o < BLK; o <<= 1) {
        int u = (t >= o) ? s[t - o] : 0;
        __syncthreads();
        s[t] += u;
        __syncthreads();
    }
    if (gid < n) offs[gid] = s[t] - v;       // exclusive, block-local
    if (t == BLK - 1) bsum[blockIdx.x] = s[t];
}

__global__ __launch_bounds__(BLK) void scan23(
    int* __restrict__ offs, const int* __restrict__ bsum,
    int n, int total, int nb) {
    __shared__ int sb[BLK];
    const int t = threadIdx.x;
    const int v = (t < nb) ? bsum[t] : 0;
    sb[t] = v;
    __syncthreads();
#pragma unroll
    for (int o = 1; o < BLK; o <<= 1) {
        int u = (t >= o) ? sb[t - o] : 0;
        __syncthreads();
        sb[t] += u;
        __syncthreads();
    }
    sb[t] -= v;                               // exclusive
    __syncthreads();
    const int base = sb[blockIdx.x];
    const int gid = blockIdx.x * BLK + t;
    if (gid < n) offs[gid] += base;
    if (gid == 0) offs[n] = total;
}

// ---------------- K4: bucket write (pass 2, exact positions) -----------------
__global__ __launch_bounds__(BLK) void bucket_write(
    const int* __restrict__ ei_raw, const int* __restrict__ boffs,
    uint2* __restrict__ tmp, int n_edges, int nbB, int nbBucket) {
    __shared__ int s_is64;
    __shared__ int bh[NBUCKET];
    __shared__ int gbase[NBUCKET];
    const int t = threadIdx.x;
    if (t == 0) {
        int all0 = 1;
        for (int i = 1; i < 128; i += 2) all0 &= (ei_raw[i] == 0);
        s_is64 = all0;
    }
    if (t < NBUCKET) bh[t] = 0;
    const int blk = blockIdx.x;
    for (int b = t; b < nbBucket; b += BLK)
        gbase[b] = boffs[(size_t)b * nbB + blk];
    __syncthreads();
    const int e0 = blk * EPB;
    const int is64 = s_is64;
    const long long* e64 = (const long long*)ei_raw;
#pragma unroll
    for (int i = 0; i < 8; ++i) {
        const int e = e0 + i * BLK + t;
        if (e < n_edges) {
            int s, d;
            if (is64) { s = (int)e64[e]; d = (int)e64[n_edges + e]; }
            else      { s = ei_raw[e];   d = ei_raw[n_edges + e]; }
            const int b = d >> 9;
            const int r = atomicAdd(&bh[b], 1);        // LDS atomic only
            tmp[gbase[b] + r] = make_uint2((unsigned)s, (unsigned)d);
        }
    }
}

// ---------------- K5: per-bucket sort + offs production ----------------------
// One block per bucket (exclusive 512-node range). LDS histogram -> LDS pair
// scan -> coalesced offs write -> in-bucket scatter of sorted_src.
__global__ __launch_bounds__(BLK) void scatter2(
    const uint2* __restrict__ tmp, const int* __restrict__ boffs,
    int* __restrict__ offs, int* __restrict__ sorted_src,
    int n_nodes, int n_edges, int nbB, int nbBucket) {
    __shared__ int lcnt[NPB];
    __shared__ int lofs[NPB];
    __shared__ int s2[BLK];
    const int b = blockIdx.x;
    const int dbase = b << 9;
    const int ncount = min(NPB, n_nodes - dbase);
    const int t = threadIdx.x;
    const int bucket_base = boffs[(size_t)b * nbB];
    const int next_base = (b + 1 < nbBucket) ? boffs[(size_t)(b + 1) * nbB] : n_edges;
    const int cntb = next_base - bucket_base;

    lcnt[t] = 0; lcnt[t + BLK] = 0;
    __syncthreads();
    const uint2* tb = tmp + bucket_base;
    for (int i = t; i < cntb; i += BLK)
        atomicAdd(&lcnt[(int)tb[i].y - dbase], 1);
    __syncthreads();

    // exclusive scan over 512 via 256 pair-sums
    s2[t] = lcnt[2 * t] + lcnt[2 * t + 1];
    __syncthreads();
#pragma unroll
    for (int o = 1; o < BLK; o <<= 1) {
        int u = (t >= o) ? s2[t - o] : 0;
        __syncthreads();
        s2[t] += u;
        __syncthreads();
    }
    const int pbase = (t > 0) ? s2[t - 1] : 0;   // exclusive pair prefix
    lofs[2 * t] = pbase;
    lofs[2 * t + 1] = pbase + lcnt[2 * t];
    __syncthreads();

    // offs (coalesced) + reset counters for the placement pass
    for (int k = t; k < ncount; k += BLK)
        offs[dbase + k] = bucket_base + lofs[k];
    if (b == nbBucket - 1 && t == 0) offs[n_nodes] = n_edges;
    lcnt[t] = 0; lcnt[t + BLK] = 0;
    __syncthreads();

    for (int i = t; i < cntb; i += BLK) {
        const uint2 p = tb[i];
        const int dl = (int)p.y - dbase;
        const int pos = bucket_base + lofs[dl] + atomicAdd(&lcnt[dl], 1);
        sorted_src[pos] = (int)p.x;
    }
}

// ---------------- K6: gather aggregation + finalize (round-9 verbatim) -------
__global__ __launch_bounds__(BLK) void aggregate_kernel(
    const int* __restrict__ sorted_src, const int* __restrict__ offs,
    const unsigned short* __restrict__ h16,
    const float* __restrict__ a_src, const float* __restrict__ a_dst,
    float* __restrict__ out, int n_nodes) {
    const int g = threadIdx.x >> 4;          // group in block: 0..15
    const int q = threadIdx.x & 15;          // lane in group
    const int d = blockIdx.x * 16 + g;
    if (d >= n_nodes) return;
    const int head = q >> 2;
    const float ad = a_dst[d * 4 + head];
    const int beg = offs[d], end = offs[d + 1];

    // self-loop seed
    float e = a_src[d * 4 + head] + ad;
    e = e > 0.f ? e : 0.2f * e;
    const float w = __expf(e);
    float den = w;
    float acc0, acc1, acc2, acc3;
    {
        const ushort4 hp = *reinterpret_cast<const ushort4*>(
            h16 + (size_t)d * 64 + q * 4);
        acc0 = w * fh2f(hp.x); acc1 = w * fh2f(hp.y);
        acc2 = w * fh2f(hp.z); acc3 = w * fh2f(hp.w);
    }

#pragma unroll 4
    for (int j = beg; j < end; ++j) {
        const int s = sorted_src[j];
        float es = a_src[s * 4 + head] + ad;
        es = es > 0.f ? es : 0.2f * es;
        const float ww = __expf(es);
        const ushort4 hp = *reinterpret_cast<const ushort4*>(
            h16 + (size_t)s * 64 + q * 4);
        acc0 = fmaf(ww, fh2f(hp.x), acc0);
        acc1 = fmaf(ww, fh2f(hp.y), acc1);
        acc2 = fmaf(ww, fh2f(hp.z), acc2);
        acc3 = fmaf(ww, fh2f(hp.w), acc3);
        den += ww;
    }

    float* op = out + (size_t)d * 64 + q * 4;
    const float4 b = *reinterpret_cast<const float4*>(op);
    const float inv = 1.f / den;
    float r0 = fmaf(acc0, inv, b.x);
    float r1 = fmaf(acc1, inv, b.y);
    float r2 = fmaf(acc2, inv, b.z);
    float r3 = fmaf(acc3, inv, b.w);
    float4 r;
    r.x = r0 > 0.f ? r0 : 0.1f * expm1f(r0);
    r.y = r1 > 0.f ? r1 : 0.1f * expm1f(r1);
    r.z = r2 > 0.f ? r2 : 0.1f * expm1f(r2);
    r.w = r3 > 0.f ? r3 : 0.1f * expm1f(r3);
    *reinterpret_cast<float4*>(op) = r;
}

extern "C" void kernel_launch(void* const* d_in, const int* in_sizes, int n_in,
                              void* d_out, int out_size, void* d_ws, size_t ws_size,
                              hipStream_t stream) {
    const float* x         = (const float*)d_in[0];
    const int*   ei_raw    = (const int*)d_in[1];
    const float* W         = (const float*)d_in[2];
    const float* att_src   = (const float*)d_in[3];
    const float* att_dst   = (const float*)d_in[4];
    const float* conv_bias = (const float*)d_in[5];
    const float* skip_W    = (const float*)d_in[6];
    const float* skip_b    = (const float*)d_in[7];

    const int n_nodes = in_sizes[0] / 64;   // 50000
    const int n_edges = in_sizes[1] / 2;    // 800000

    const int nbNode = (n_nodes + 63) / 64;                 // 782
    const int nbB = (n_edges + EPB - 1) / EPB;              // 391
    const int nbBucket = (n_nodes + NPB - 1) / NPB;         // 98
    const int cntN = nbBucket * nbB;                        // 38318
    const int nb_c = (cntN + BLK - 1) / BLK;                // 150

    float* ws = (float*)d_ws;
    unsigned short* wfrag = (unsigned short*)ws;            // 8192 u16
    float* bias64 = ws + 4096;                              // 64
    float* watt_s = bias64 + 64;                            // 256
    float* watt_d = watt_s + 256;                           // 256
    uint2* tmp    = (uint2*)(watt_d + 256);                 // E uint2 (8B-aligned)
    unsigned short* h16 = (unsigned short*)(tmp + n_edges); // N*64 u16
    float* a_src  = (float*)(h16 + (size_t)n_nodes * 64);   // N*4
    float* a_dst  = a_src + (size_t)n_nodes * 4;            // N*4
    int*   blockcnt = (int*)(a_dst + (size_t)n_nodes * 4);  // cntN (+1 for scan23 tail)
    int*   bsum   = blockcnt + cntN + 1;                    // 256
    int*   offs   = bsum + 256;                             // N+1
    int*   sorted_src = offs + n_nodes + 1;                 // E
    float* base   = (float*)d_out;

    prep_weights<<<1, BLK, 0, stream>>>(W, skip_W, conv_bias, skip_b,
                                        att_src, att_dst, wfrag, bias64,
                                        watt_s, watt_d);

    node_bcount<<<nbNode + nbB, BLK, 0, stream>>>(
        x, wfrag, bias64, watt_s, watt_d, h16, base, a_src, a_dst, n_nodes,
        ei_raw, blockcnt, n_edges, nbNode, nbB, nbBucket);

    scan1<<<nb_c, BLK, 0, stream>>>(blockcnt, blockcnt, bsum, cntN);
    scan23<<<nb_c, BLK, 0, stream>>>(blockcnt, bsum, cntN, n_edges, nb_c);

    bucket_write<<<nbB, BLK, 0, stream>>>(ei_raw, blockcnt, tmp,
                                          n_edges, nbB, nbBucket);
    scatter2<<<nbBucket, BLK, 0, stream>>>(tmp, blockcnt, offs, sorted_src,
                                           n_nodes, n_edges, nbB, nbBucket);

    aggregate_kernel<<<(n_nodes + 15) / 16, BLK, 0, stream>>>(
        sorted_src, offs, h16, a_src, a_dst, (float*)d_out, n_nodes);
}